// Round 1
// baseline (2100.389 us; speedup 1.0000x reference)
//
#include <hip/hip_runtime.h>
#include <cstdint>

#define NN 20000
#define EE 320000
#define DHID 256

// ---------------------------------------------------------------- utilities

__device__ __forceinline__ float wave_sum(float v) {
#pragma unroll
    for (int m = 1; m < 64; m <<= 1) v += __shfl_xor(v, m);
    return v;
}

__device__ __forceinline__ float wave_max(float v) {
#pragma unroll
    for (int m = 1; m < 64; m <<= 1) v = fmaxf(v, __shfl_xor(v, m));
    return v;
}

__device__ __forceinline__ float gelu_f(float x) {
    // tanh approximation (matches jax.nn.gelu approximate=True)
    float z = 0.7978845608028654f * (x + 0.044715f * x * x * x);
    float e = __expf(2.0f * z);
    float t = 1.0f - 2.0f / (e + 1.0f);   // tanh(z), saturates correctly at +/-1
    return 0.5f * x * (1.0f + t);
}

// ---------------------------------------------------------------- CSR build

__global__ void hist_kernel(const int* __restrict__ edges, int* __restrict__ counts, int E_) {
    int e = blockIdx.x * 256 + threadIdx.x;
    if (e >= E_) return;
    atomicAdd(&counts[edges[e * 2]], 1);
}

__global__ __launch_bounds__(1024) void scan_kernel(const int* __restrict__ counts,
                                                    int* __restrict__ indptr,
                                                    int* __restrict__ cursor, int n) {
    __shared__ int sdata[1024];
    __shared__ int s_running;
    int tid = threadIdx.x;
    if (tid == 0) s_running = 0;
    __syncthreads();
    for (int base = 0; base < n; base += 1024) {
        int i = base + tid;
        int c = (i < n) ? counts[i] : 0;
        sdata[tid] = c;
        __syncthreads();
#pragma unroll
        for (int off = 1; off < 1024; off <<= 1) {
            int v = (tid >= off) ? sdata[tid - off] : 0;
            __syncthreads();
            sdata[tid] += v;
            __syncthreads();
        }
        int incl = sdata[tid];
        int running = s_running;
        if (i < n) {
            int excl = running + incl - c;
            indptr[i] = excl;
            cursor[i] = excl;
        }
        __syncthreads();
        if (tid == 1023) s_running = running + incl;
        __syncthreads();
    }
    if (tid == 0) indptr[n] = s_running;
}

__global__ void scatter_kernel(const int* __restrict__ edges, int* __restrict__ cursor,
                               int* __restrict__ ssrc, int* __restrict__ sdst, int E_) {
    int e = blockIdx.x * 256 + threadIdx.x;
    if (e >= E_) return;
    int dstn = edges[e * 2];
    int src  = edges[e * 2 + 1];
    int pos = atomicAdd(&cursor[dstn], 1);
    ssrc[pos] = src;
    sdst[pos] = dstn;
}

// ---------------------------------------------------------------- LayerNorm

__global__ __launch_bounds__(256) void ln_kernel(const float* __restrict__ X,
                                                 const float* __restrict__ g,
                                                 const float* __restrict__ b,
                                                 float* __restrict__ Y, int nrows) {
    int row = blockIdx.x * 4 + (threadIdx.x >> 6);
    int lane = threadIdx.x & 63;
    if (row >= nrows) return;
    float4 v = *(const float4*)(X + (size_t)row * DHID + lane * 4);
    float sum = v.x + v.y + v.z + v.w;
    float sq = v.x * v.x + v.y * v.y + v.z * v.z + v.w * v.w;
    sum = wave_sum(sum);
    sq  = wave_sum(sq);
    float mean = sum * (1.0f / DHID);
    float var  = sq * (1.0f / DHID) - mean * mean;
    float r = rsqrtf(var + 1e-3f);
    float4 gv = *(const float4*)(g + lane * 4);
    float4 bv = *(const float4*)(b + lane * 4);
    float4 o;
    o.x = (v.x - mean) * r * gv.x + bv.x;
    o.y = (v.y - mean) * r * gv.y + bv.y;
    o.z = (v.z - mean) * r * gv.z + bv.z;
    o.w = (v.w - mean) * r * gv.w + bv.w;
    *(float4*)(Y + (size_t)row * DHID + lane * 4) = o;
}

// ---------------------------------------------------------------- fp32 GEMM (A:nrows x 256 @ W:256 x M -> C:nrows x M)

__global__ __launch_bounds__(256) void gemm64(const float* __restrict__ A,
                                              const float* __restrict__ W,
                                              const float* __restrict__ bias,
                                              float* __restrict__ C, int nrows, int M) {
    __shared__ float As[16][65];
    __shared__ float Ws[16][64];
    const int bm = blockIdx.x * 64;
    const int bn = blockIdx.y * 64;
    const int tid = threadIdx.x;
    const int ar = tid >> 2, ac = (tid & 3) << 2;
    const int wr = tid >> 4, wc = (tid & 15) << 2;
    const int ty = tid >> 4, tx = tid & 15;
    int arow = bm + ar;
    if (arow >= nrows) arow = nrows - 1;
    float acc[4][4] = {};
    for (int k0 = 0; k0 < 256; k0 += 16) {
        float4 av = *(const float4*)(A + (size_t)arow * 256 + k0 + ac);
        As[ac + 0][ar] = av.x;
        As[ac + 1][ar] = av.y;
        As[ac + 2][ar] = av.z;
        As[ac + 3][ar] = av.w;
        *(float4*)(&Ws[wr][wc]) = *(const float4*)(W + (size_t)(k0 + wr) * M + bn + wc);
        __syncthreads();
#pragma unroll
        for (int k = 0; k < 16; ++k) {
            float a0 = As[k][ty * 4 + 0];
            float a1 = As[k][ty * 4 + 1];
            float a2 = As[k][ty * 4 + 2];
            float a3 = As[k][ty * 4 + 3];
            float4 w = *(const float4*)(&Ws[k][tx * 4]);
            acc[0][0] += a0 * w.x; acc[0][1] += a0 * w.y; acc[0][2] += a0 * w.z; acc[0][3] += a0 * w.w;
            acc[1][0] += a1 * w.x; acc[1][1] += a1 * w.y; acc[1][2] += a1 * w.z; acc[1][3] += a1 * w.w;
            acc[2][0] += a2 * w.x; acc[2][1] += a2 * w.y; acc[2][2] += a2 * w.z; acc[2][3] += a2 * w.w;
            acc[3][0] += a3 * w.x; acc[3][1] += a3 * w.y; acc[3][2] += a3 * w.z; acc[3][3] += a3 * w.w;
        }
        __syncthreads();
    }
    float4 bv = make_float4(0.f, 0.f, 0.f, 0.f);
    if (bias) bv = *(const float4*)(bias + bn + tx * 4);
#pragma unroll
    for (int i = 0; i < 4; ++i) {
        int row = bm + ty * 4 + i;
        if (row < nrows) {
            float4 o;
            o.x = acc[i][0] + bv.x;
            o.y = acc[i][1] + bv.y;
            o.z = acc[i][2] + bv.z;
            o.w = acc[i][3] + bv.w;
            *(float4*)(C + (size_t)row * M + bn + tx * 4) = o;
        }
    }
}

// ---------------------------------------------------------------- fused dense: C = sum_c gelu(A@W[:,c*256+j] + b) + A

__global__ __launch_bounds__(256) void dense_fused(const float* __restrict__ A,
                                                   const float* __restrict__ W,
                                                   const float* __restrict__ bias,
                                                   float* __restrict__ C, int nrows) {
    __shared__ float As[16][65];
    __shared__ float Ws[16][64];
    const int bm = blockIdx.x * 64;
    const int bn = blockIdx.y * 64;
    const int tid = threadIdx.x;
    const int ar = tid >> 2, ac = (tid & 3) << 2;
    const int wr = tid >> 4, wc = (tid & 15) << 2;
    const int ty = tid >> 4, tx = tid & 15;
    int arow = bm + ar;
    if (arow >= nrows) arow = nrows - 1;
    float out[4][4] = {};
    for (int c = 0; c < 4; ++c) {
        float acc[4][4] = {};
        const int coloff = c * 256 + bn;
        for (int k0 = 0; k0 < 256; k0 += 16) {
            float4 av = *(const float4*)(A + (size_t)arow * 256 + k0 + ac);
            As[ac + 0][ar] = av.x;
            As[ac + 1][ar] = av.y;
            As[ac + 2][ar] = av.z;
            As[ac + 3][ar] = av.w;
            *(float4*)(&Ws[wr][wc]) = *(const float4*)(W + (size_t)(k0 + wr) * 1024 + coloff + wc);
            __syncthreads();
#pragma unroll
            for (int k = 0; k < 16; ++k) {
                float a0 = As[k][ty * 4 + 0];
                float a1 = As[k][ty * 4 + 1];
                float a2 = As[k][ty * 4 + 2];
                float a3 = As[k][ty * 4 + 3];
                float4 w = *(const float4*)(&Ws[k][tx * 4]);
                acc[0][0] += a0 * w.x; acc[0][1] += a0 * w.y; acc[0][2] += a0 * w.z; acc[0][3] += a0 * w.w;
                acc[1][0] += a1 * w.x; acc[1][1] += a1 * w.y; acc[1][2] += a1 * w.z; acc[1][3] += a1 * w.w;
                acc[2][0] += a2 * w.x; acc[2][1] += a2 * w.y; acc[2][2] += a2 * w.z; acc[2][3] += a2 * w.w;
                acc[3][0] += a3 * w.x; acc[3][1] += a3 * w.y; acc[3][2] += a3 * w.z; acc[3][3] += a3 * w.w;
            }
            __syncthreads();
        }
        float4 bv = *(const float4*)(bias + coloff + tx * 4);
#pragma unroll
        for (int i = 0; i < 4; ++i) {
            out[i][0] += gelu_f(acc[i][0] + bv.x);
            out[i][1] += gelu_f(acc[i][1] + bv.y);
            out[i][2] += gelu_f(acc[i][2] + bv.z);
            out[i][3] += gelu_f(acc[i][3] + bv.w);
        }
    }
#pragma unroll
    for (int i = 0; i < 4; ++i) {
        int row = bm + ty * 4 + i;
        if (row < nrows) {
            float4 res = *(const float4*)(A + (size_t)row * 256 + bn + tx * 4);
            float4 o;
            o.x = out[i][0] + res.x;
            o.y = out[i][1] + res.y;
            o.z = out[i][2] + res.z;
            o.w = out[i][3] + res.w;
            *(float4*)(C + (size_t)row * 256 + bn + tx * 4) = o;
        }
    }
}

// ---------------------------------------------------------------- edge scores: s[p][h] = sum_u att[h][u]*leaky(zl[dst]+zr[src])

__global__ __launch_bounds__(256) void scores_kernel(const float* __restrict__ zl,
                                                     const float* __restrict__ zr,
                                                     const float* __restrict__ att,
                                                     const int* __restrict__ ssrc,
                                                     const int* __restrict__ sdst,
                                                     float* __restrict__ s, int E_) {
    int w = threadIdx.x >> 6;
    int lane = threadIdx.x & 63;
    int p = blockIdx.x * 4 + w;
    if (p >= E_) return;
    int src = ssrc[p];
    int dstn = sdst[p];
    const float* zlrow = zl + (size_t)dstn * 256;
    const float* zrrow = zr + (size_t)src * 256;
#pragma unroll
    for (int h = 0; h < 4; ++h) {
        float v = zlrow[h * 64 + lane] + zrrow[h * 64 + lane];
        v = (v > 0.f) ? v : 0.2f * v;
        float prod = att[h * 64 + lane] * v;
        prod = wave_sum(prod);
        if (lane == 0) s[p * 4 + h] = prod;
    }
}

// ---------------------------------------------------------------- per-node softmax + aggregation + residual

__global__ __launch_bounds__(256) void agg_kernel(const float* __restrict__ s,
                                                  const int* __restrict__ ssrc,
                                                  const int* __restrict__ indptr,
                                                  const float* __restrict__ zr,
                                                  const float* __restrict__ hn,
                                                  float* __restrict__ hout, int nrows) {
    int n = blockIdx.x;
    if (n >= nrows) return;
    int h = threadIdx.x >> 6;
    int lane = threadIdx.x & 63;
    int start = indptr[n];
    int end = indptr[n + 1];
    float m = -3.0e38f;
    for (int p = start + lane; p < end; p += 64) m = fmaxf(m, s[p * 4 + h]);
    m = wave_max(m);
    float denom = 0.f;
    float acc = 0.f;
    for (int p = start; p < end; ++p) {
        float es = __expf(s[p * 4 + h] - m);
        denom += es;
        int src = ssrc[p];
        acc += es * zr[(size_t)src * 256 + h * 64 + lane];
    }
    int idx = n * 256 + h * 64 + lane;
    hout[idx] = acc / (denom + 1e-9f) + hn[idx];
}

// ---------------------------------------------------------------- host

extern "C" void kernel_launch(void* const* d_in, const int* in_sizes, int n_in,
                              void* d_out, int out_size, void* d_ws, size_t ws_size,
                              hipStream_t stream) {
    const float* x       = (const float*)d_in[0];
    const float* head_W  = (const float*)d_in[1];
    const float* head_b  = (const float*)d_in[2];
    const float* ng_g    = (const float*)d_in[3];
    const float* ng_b    = (const float*)d_in[4];
    const float* Wl      = (const float*)d_in[5];
    const float* Wr      = (const float*)d_in[6];
    const float* att     = (const float*)d_in[7];
    const float* nd_g    = (const float*)d_in[8];
    const float* nd_b    = (const float*)d_in[9];
    const float* dense_W = (const float*)d_in[10];
    const float* dense_b = (const float*)d_in[11];
    const float* tail_W  = (const float*)d_in[12];
    const float* tail_b  = (const float*)d_in[13];
    const int*   edges   = (const int*)d_in[14];
    float* out = (float*)d_out;

    float* ws = (float*)d_ws;
    float* h  = ws;
    float* hn = h + (size_t)NN * DHID;
    float* zl = hn + (size_t)NN * DHID;
    float* zr = zl + (size_t)NN * DHID;
    float* s  = zr + (size_t)NN * DHID;
    int* counts = (int*)(s + (size_t)EE * 4);
    int* indptr = counts + NN;
    int* cursor = indptr + NN + 1;
    int* ssrc   = cursor + NN;
    int* sdst   = ssrc + EE;

    // CSR build (edges identical across layers)
    hipMemsetAsync(counts, 0, NN * sizeof(int), stream);
    hist_kernel<<<(EE + 255) / 256, 256, 0, stream>>>(edges, counts, EE);
    scan_kernel<<<1, 1024, 0, stream>>>(counts, indptr, cursor, NN);
    scatter_kernel<<<(EE + 255) / 256, 256, 0, stream>>>(edges, cursor, ssrc, sdst, EE);

    dim3 g256((NN + 63) / 64, 4);
    // h = x @ head_W + head_b
    gemm64<<<g256, 256, 0, stream>>>(x, head_W, head_b, h, NN, 256);

    for (int l = 0; l < 4; ++l) {
        ln_kernel<<<NN / 4, 256, 0, stream>>>(h, ng_g + l * 256, ng_b + l * 256, hn, NN);
        gemm64<<<g256, 256, 0, stream>>>(hn, Wl + (size_t)l * 65536, nullptr, zl, NN, 256);
        gemm64<<<g256, 256, 0, stream>>>(hn, Wr + (size_t)l * 65536, nullptr, zr, NN, 256);
        scores_kernel<<<(EE + 3) / 4, 256, 0, stream>>>(zl, zr, att + l * 256, ssrc, sdst, s, EE);
        agg_kernel<<<NN, 256, 0, stream>>>(s, ssrc, indptr, zr, hn, h, NN);
        ln_kernel<<<NN / 4, 256, 0, stream>>>(h, nd_g + l * 256, nd_b + l * 256, hn, NN);
        dense_fused<<<g256, 256, 0, stream>>>(hn, dense_W + (size_t)l * 262144, dense_b + l * 1024, h, NN);
    }
    // out = h @ tail_W + tail_b
    gemm64<<<dim3((NN + 63) / 64, 1), 256, 0, stream>>>(h, tail_W, tail_b, out, NN, 64);
}

// Round 2
// 1254.350 us; speedup vs baseline: 1.6745x; 1.6745x over previous
//
#include <hip/hip_runtime.h>
#include <cstdint>

#define NN 20000
#define EE 320000
#define DHID 256

typedef short bf16x8 __attribute__((ext_vector_type(8)));
typedef float f32x4 __attribute__((ext_vector_type(4)));

// ---------------------------------------------------------------- utilities

__device__ __forceinline__ float b2f(unsigned short u) {
    union { unsigned int i; float f; } v;
    v.i = ((unsigned int)u) << 16;
    return v.f;
}

__device__ __forceinline__ unsigned short f2b(float x) {
    union { float f; unsigned int i; } v;
    v.f = x;
    unsigned int r = (v.i + 0x7FFFu + ((v.i >> 16) & 1u)) >> 16;
    return (unsigned short)r;
}

__device__ __forceinline__ float wave_sum(float v) {
#pragma unroll
    for (int m = 1; m < 64; m <<= 1) v += __shfl_xor(v, m);
    return v;
}

__device__ __forceinline__ float gelu_f(float x) {
    float z = 0.7978845608028654f * (x + 0.044715f * x * x * x);
    float e = __expf(2.0f * z);
    float t = 1.0f - 2.0f / (e + 1.0f);   // tanh(z)
    return 0.5f * x * (1.0f + t);
}

// ---------------------------------------------------------------- CSR build

__global__ void hist_kernel(const int* __restrict__ edges, int* __restrict__ counts, int E_) {
    int e = blockIdx.x * 256 + threadIdx.x;
    if (e >= E_) return;
    atomicAdd(&counts[edges[e * 2]], 1);
}

__global__ __launch_bounds__(1024) void scan_kernel(const int* __restrict__ counts,
                                                    int* __restrict__ indptr,
                                                    int* __restrict__ cursor, int n) {
    __shared__ int sdata[1024];
    __shared__ int s_running;
    int tid = threadIdx.x;
    if (tid == 0) s_running = 0;
    __syncthreads();
    for (int base = 0; base < n; base += 1024) {
        int i = base + tid;
        int c = (i < n) ? counts[i] : 0;
        sdata[tid] = c;
        __syncthreads();
#pragma unroll
        for (int off = 1; off < 1024; off <<= 1) {
            int v = (tid >= off) ? sdata[tid - off] : 0;
            __syncthreads();
            sdata[tid] += v;
            __syncthreads();
        }
        int incl = sdata[tid];
        int running = s_running;
        if (i < n) {
            int excl = running + incl - c;
            indptr[i] = excl;
            cursor[i] = excl;
        }
        __syncthreads();
        if (tid == 1023) s_running = running + incl;
        __syncthreads();
    }
    if (tid == 0) indptr[n] = s_running;
}

__global__ void scatter_kernel(const int* __restrict__ edges, int* __restrict__ cursor,
                               int* __restrict__ ssrc, int* __restrict__ sdst, int E_) {
    int e = blockIdx.x * 256 + threadIdx.x;
    if (e >= E_) return;
    int dstn = edges[e * 2];
    int src  = edges[e * 2 + 1];
    int pos = atomicAdd(&cursor[dstn], 1);
    ssrc[pos] = src;
    sdst[pos] = dstn;
}

// ---------------------------------------------------------------- weight transpose + bf16 convert: W (K x M) -> Wt (M x K)

__global__ __launch_bounds__(256) void transpose_bf16(const float* __restrict__ W,
                                                      unsigned short* __restrict__ Wt,
                                                      int K, int M) {
    int l = blockIdx.z;
    W  += (size_t)l * K * M;
    Wt += (size_t)l * M * K;
    __shared__ float sm[32][33];
    int m0 = blockIdx.x * 32, k0 = blockIdx.y * 32;
    int tx = threadIdx.x & 31, ty = threadIdx.x >> 5;
#pragma unroll
    for (int i = 0; i < 4; ++i)
        sm[ty + i * 8][tx] = W[(size_t)(k0 + ty + i * 8) * M + m0 + tx];
    __syncthreads();
#pragma unroll
    for (int i = 0; i < 4; ++i)
        Wt[(size_t)(m0 + ty + i * 8) * K + k0 + tx] = f2b(sm[tx][ty + i * 8]);
}

__global__ void convert_bf16(const float* __restrict__ in, unsigned short* __restrict__ out, int n4) {
    int i = blockIdx.x * 256 + threadIdx.x;
    if (i >= n4) return;
    float4 v = *(const float4*)(in + (size_t)i * 4);
    ushort4 o;
    o.x = f2b(v.x); o.y = f2b(v.y); o.z = f2b(v.z); o.w = f2b(v.w);
    *(ushort4*)(out + (size_t)i * 4) = o;
}

// ---------------------------------------------------------------- LayerNorm (fp32 in -> fp32 + bf16 out)

__global__ __launch_bounds__(256) void ln_kernel(const float* __restrict__ X,
                                                 const float* __restrict__ g,
                                                 const float* __restrict__ b,
                                                 float* __restrict__ Y,
                                                 unsigned short* __restrict__ Yb, int nrows) {
    int row = blockIdx.x * 4 + (threadIdx.x >> 6);
    int lane = threadIdx.x & 63;
    if (row >= nrows) return;
    float4 v = *(const float4*)(X + (size_t)row * DHID + lane * 4);
    float sum = v.x + v.y + v.z + v.w;
    float sq = v.x * v.x + v.y * v.y + v.z * v.z + v.w * v.w;
    sum = wave_sum(sum);
    sq  = wave_sum(sq);
    float mean = sum * (1.0f / DHID);
    float var  = sq * (1.0f / DHID) - mean * mean;
    float r = rsqrtf(var + 1e-3f);
    float4 gv = *(const float4*)(g + lane * 4);
    float4 bv = *(const float4*)(b + lane * 4);
    float4 o;
    o.x = (v.x - mean) * r * gv.x + bv.x;
    o.y = (v.y - mean) * r * gv.y + bv.y;
    o.z = (v.z - mean) * r * gv.z + bv.z;
    o.w = (v.w - mean) * r * gv.w + bv.w;
    *(float4*)(Y + (size_t)row * DHID + lane * 4) = o;
    ushort4 ob;
    ob.x = f2b(o.x); ob.y = f2b(o.y); ob.z = f2b(o.z); ob.w = f2b(o.w);
    *(ushort4*)(Yb + (size_t)row * DHID + lane * 4) = ob;
}

// ---------------------------------------------------------------- MFMA GEMM: C(nrows x M) = A(nrows x 256) @ Wt^T + bias
// A bf16 row-major (k contig); Wt bf16 (M x 256, k contig). fp32 out.

__global__ __launch_bounds__(256) void gemm_mfma_f32(const unsigned short* __restrict__ A,
                                                     const unsigned short* __restrict__ Wt,
                                                     const float* __restrict__ bias,
                                                     float* __restrict__ C, int nrows, int M) {
    int tid = threadIdx.x;
    int wid = tid >> 6, lane = tid & 63;
    int quad = lane >> 4, l16 = lane & 15;
    int bm = blockIdx.x * 128 + (wid >> 1) * 64;
    int bn = blockIdx.y * 128 + (wid & 1) * 64;
    int arow[4], bcol[4];
#pragma unroll
    for (int mi = 0; mi < 4; ++mi) arow[mi] = min(bm + mi * 16 + l16, nrows - 1);
#pragma unroll
    for (int ni = 0; ni < 4; ++ni) bcol[ni] = min(bn + ni * 16 + l16, M - 1);
    f32x4 acc[4][4] = {};
    for (int k0 = 0; k0 < 256; k0 += 32) {
        bf16x8 a[4], b[4];
#pragma unroll
        for (int mi = 0; mi < 4; ++mi)
            a[mi] = *(const bf16x8*)(A + (size_t)arow[mi] * 256 + k0 + quad * 8);
#pragma unroll
        for (int ni = 0; ni < 4; ++ni)
            b[ni] = *(const bf16x8*)(Wt + (size_t)bcol[ni] * 256 + k0 + quad * 8);
#pragma unroll
        for (int mi = 0; mi < 4; ++mi)
#pragma unroll
            for (int ni = 0; ni < 4; ++ni)
                acc[mi][ni] = __builtin_amdgcn_mfma_f32_16x16x32_bf16(a[mi], b[ni], acc[mi][ni], 0, 0, 0);
    }
#pragma unroll
    for (int ni = 0; ni < 4; ++ni) {
        int col = bn + ni * 16 + l16;
        if (col >= M) continue;
        float bv = bias ? bias[col] : 0.0f;
#pragma unroll
        for (int mi = 0; mi < 4; ++mi) {
#pragma unroll
            for (int r = 0; r < 4; ++r) {
                int row = bm + mi * 16 + quad * 4 + r;
                if (row < nrows) C[(size_t)row * M + col] = acc[mi][ni][r] + bv;
            }
        }
    }
}

// same but bf16 output (for zl/zr), no bias, M=256 fixed
__global__ __launch_bounds__(256) void gemm_mfma_b16(const unsigned short* __restrict__ A,
                                                     const unsigned short* __restrict__ Wt,
                                                     unsigned short* __restrict__ C, int nrows) {
    int tid = threadIdx.x;
    int wid = tid >> 6, lane = tid & 63;
    int quad = lane >> 4, l16 = lane & 15;
    int bm = blockIdx.x * 128 + (wid >> 1) * 64;
    int bn = blockIdx.y * 128 + (wid & 1) * 64;
    int arow[4];
#pragma unroll
    for (int mi = 0; mi < 4; ++mi) arow[mi] = min(bm + mi * 16 + l16, nrows - 1);
    f32x4 acc[4][4] = {};
    for (int k0 = 0; k0 < 256; k0 += 32) {
        bf16x8 a[4], b[4];
#pragma unroll
        for (int mi = 0; mi < 4; ++mi)
            a[mi] = *(const bf16x8*)(A + (size_t)arow[mi] * 256 + k0 + quad * 8);
#pragma unroll
        for (int ni = 0; ni < 4; ++ni)
            b[ni] = *(const bf16x8*)(Wt + (size_t)(bn + ni * 16 + l16) * 256 + k0 + quad * 8);
#pragma unroll
        for (int mi = 0; mi < 4; ++mi)
#pragma unroll
            for (int ni = 0; ni < 4; ++ni)
                acc[mi][ni] = __builtin_amdgcn_mfma_f32_16x16x32_bf16(a[mi], b[ni], acc[mi][ni], 0, 0, 0);
    }
#pragma unroll
    for (int ni = 0; ni < 4; ++ni) {
        int col = bn + ni * 16 + l16;
#pragma unroll
        for (int mi = 0; mi < 4; ++mi) {
#pragma unroll
            for (int r = 0; r < 4; ++r) {
                int row = bm + mi * 16 + quad * 4 + r;
                if (row < nrows) C[(size_t)row * 256 + col] = f2b(acc[mi][ni][r]);
            }
        }
    }
}

// ---------------------------------------------------------------- fused dense MFMA: H = sum_c gelu(A@Wc + bc) + res, bf16 copy

__global__ __launch_bounds__(256) void dense_mfma(const unsigned short* __restrict__ A,
                                                  const unsigned short* __restrict__ Wt,
                                                  const float* __restrict__ bias,
                                                  const float* __restrict__ res,
                                                  float* __restrict__ H,
                                                  unsigned short* __restrict__ Hb, int nrows) {
    int tid = threadIdx.x;
    int wid = tid >> 6, lane = tid & 63;
    int quad = lane >> 4, l16 = lane & 15;
    int bm = blockIdx.x * 128 + (wid >> 1) * 64;
    int bn = blockIdx.y * 128 + (wid & 1) * 64;
    int arow[4];
#pragma unroll
    for (int mi = 0; mi < 4; ++mi) arow[mi] = min(bm + mi * 16 + l16, nrows - 1);
    f32x4 out[4][4] = {};
    for (int c = 0; c < 4; ++c) {
        const unsigned short* Wc = Wt + (size_t)c * 256 * 256;
        f32x4 acc[4][4] = {};
        for (int k0 = 0; k0 < 256; k0 += 32) {
            bf16x8 a[4], b[4];
#pragma unroll
            for (int mi = 0; mi < 4; ++mi)
                a[mi] = *(const bf16x8*)(A + (size_t)arow[mi] * 256 + k0 + quad * 8);
#pragma unroll
            for (int ni = 0; ni < 4; ++ni)
                b[ni] = *(const bf16x8*)(Wc + (size_t)(bn + ni * 16 + l16) * 256 + k0 + quad * 8);
#pragma unroll
            for (int mi = 0; mi < 4; ++mi)
#pragma unroll
                for (int ni = 0; ni < 4; ++ni)
                    acc[mi][ni] = __builtin_amdgcn_mfma_f32_16x16x32_bf16(a[mi], b[ni], acc[mi][ni], 0, 0, 0);
        }
#pragma unroll
        for (int ni = 0; ni < 4; ++ni) {
            float bv = bias[c * 256 + bn + ni * 16 + l16];
#pragma unroll
            for (int mi = 0; mi < 4; ++mi)
#pragma unroll
                for (int r = 0; r < 4; ++r)
                    out[mi][ni][r] += gelu_f(acc[mi][ni][r] + bv);
        }
    }
#pragma unroll
    for (int ni = 0; ni < 4; ++ni) {
        int col = bn + ni * 16 + l16;
#pragma unroll
        for (int mi = 0; mi < 4; ++mi) {
#pragma unroll
            for (int r = 0; r < 4; ++r) {
                int row = bm + mi * 16 + quad * 4 + r;
                if (row < nrows) {
                    float v = out[mi][ni][r] + res[(size_t)row * 256 + col];
                    H[(size_t)row * 256 + col] = v;
                    Hb[(size_t)row * 256 + col] = f2b(v);
                }
            }
        }
    }
}

// ---------------------------------------------------------------- edge scores (bf16 zl/zr): s[p][h]

__global__ __launch_bounds__(256) void scores_kernel(const unsigned short* __restrict__ zl,
                                                     const unsigned short* __restrict__ zr,
                                                     const float* __restrict__ att,
                                                     const int* __restrict__ ssrc,
                                                     const int* __restrict__ sdst,
                                                     float* __restrict__ s, int E_) {
    int wid = threadIdx.x >> 6;
    int lane = threadIdx.x & 63;
    int quad = lane >> 4, l16 = lane & 15;
    int p = blockIdx.x * 4 + wid;
    if (p >= E_) return;
    int src = ssrc[p];
    int dstn = sdst[p];
    float4 a4 = *(const float4*)(att + lane * 4);
    ushort4 lv = *(const ushort4*)(zl + (size_t)dstn * 256 + lane * 4);
    ushort4 rv = *(const ushort4*)(zr + (size_t)src * 256 + lane * 4);
    float v0 = b2f(lv.x) + b2f(rv.x);
    float v1 = b2f(lv.y) + b2f(rv.y);
    float v2 = b2f(lv.z) + b2f(rv.z);
    float v3 = b2f(lv.w) + b2f(rv.w);
    v0 = (v0 > 0.f) ? v0 : 0.2f * v0;
    v1 = (v1 > 0.f) ? v1 : 0.2f * v1;
    v2 = (v2 > 0.f) ? v2 : 0.2f * v2;
    v3 = (v3 > 0.f) ? v3 : 0.2f * v3;
    float sum = a4.x * v0 + a4.y * v1 + a4.z * v2 + a4.w * v3;
#pragma unroll
    for (int m = 1; m < 16; m <<= 1) sum += __shfl_xor(sum, m);
    if (l16 == 0) s[p * 4 + quad] = sum;
}

// ---------------------------------------------------------------- per-node softmax + agg + residual (wave per node)

__global__ __launch_bounds__(256) void agg_kernel(const float* __restrict__ s,
                                                  const int* __restrict__ ssrc,
                                                  const int* __restrict__ indptr,
                                                  const unsigned short* __restrict__ zr,
                                                  const float* __restrict__ hn,
                                                  float* __restrict__ hout, int nrows) {
    int wid = threadIdx.x >> 6;
    int lane = threadIdx.x & 63;
    int quad = lane >> 4, l16 = lane & 15;
    int n = blockIdx.x * 4 + wid;
    if (n >= nrows) return;
    int start = indptr[n];
    int end = indptr[n + 1];
    float m = -3.0e38f;
    for (int p = start + l16; p < end; p += 16) m = fmaxf(m, s[p * 4 + quad]);
#pragma unroll
    for (int mm = 1; mm < 16; mm <<= 1) m = fmaxf(m, __shfl_xor(m, mm));
    float denom = 0.f;
    float ax = 0.f, ay = 0.f, az = 0.f, aw = 0.f;
    for (int p = start; p < end; ++p) {
        float es = __expf(s[p * 4 + quad] - m);
        denom += es;
        int src = ssrc[p];
        ushort4 v = *(const ushort4*)(zr + (size_t)src * 256 + lane * 4);
        ax += es * b2f(v.x);
        ay += es * b2f(v.y);
        az += es * b2f(v.z);
        aw += es * b2f(v.w);
    }
    float inv = 1.0f / (denom + 1e-9f);
    size_t idx = (size_t)n * 256 + lane * 4;
    float4 r = *(const float4*)(hn + idx);
    float4 o;
    o.x = ax * inv + r.x;
    o.y = ay * inv + r.y;
    o.z = az * inv + r.z;
    o.w = aw * inv + r.w;
    *(float4*)(hout + idx) = o;
}

// ---------------------------------------------------------------- host

extern "C" void kernel_launch(void* const* d_in, const int* in_sizes, int n_in,
                              void* d_out, int out_size, void* d_ws, size_t ws_size,
                              hipStream_t stream) {
    const float* x       = (const float*)d_in[0];
    const float* head_W  = (const float*)d_in[1];
    const float* head_b  = (const float*)d_in[2];
    const float* ng_g    = (const float*)d_in[3];
    const float* ng_b    = (const float*)d_in[4];
    const float* Wl      = (const float*)d_in[5];
    const float* Wr      = (const float*)d_in[6];
    const float* att     = (const float*)d_in[7];
    const float* nd_g    = (const float*)d_in[8];
    const float* nd_b    = (const float*)d_in[9];
    const float* dense_W = (const float*)d_in[10];
    const float* dense_b = (const float*)d_in[11];
    const float* tail_W  = (const float*)d_in[12];
    const float* tail_b  = (const float*)d_in[13];
    const int*   edges   = (const int*)d_in[14];
    float* out = (float*)d_out;

    const size_t NH = (size_t)NN * DHID;  // 5,120,000
    float* h  = (float*)d_ws;
    float* hn = h + NH;
    float* s  = hn + NH;
    unsigned short* xb     = (unsigned short*)(s + (size_t)EE * 4);  // also reused as hb
    unsigned short* hnb    = xb + NH;
    unsigned short* zlb    = hnb + NH;
    unsigned short* zrb    = zlb + NH;
    unsigned short* headT  = zrb + NH;
    unsigned short* WlT    = headT + 65536;
    unsigned short* WrT    = WlT + 262144;
    unsigned short* denseT = WrT + 262144;
    unsigned short* tailT  = denseT + 1048576;
    int* counts = (int*)(tailT + 16384);
    int* indptr = counts + NN;
    int* cursor = indptr + NN + 1;
    int* ssrc   = cursor + NN;
    int* sdst   = ssrc + EE;

    // CSR build
    hipMemsetAsync(counts, 0, NN * sizeof(int), stream);
    hist_kernel<<<(EE + 255) / 256, 256, 0, stream>>>(edges, counts, EE);
    scan_kernel<<<1, 1024, 0, stream>>>(counts, indptr, cursor, NN);
    scatter_kernel<<<(EE + 255) / 256, 256, 0, stream>>>(edges, cursor, ssrc, sdst, EE);

    // weight prep
    transpose_bf16<<<dim3(8, 8, 1), 256, 0, stream>>>(head_W, headT, 256, 256);
    transpose_bf16<<<dim3(8, 8, 4), 256, 0, stream>>>(Wl, WlT, 256, 256);
    transpose_bf16<<<dim3(8, 8, 4), 256, 0, stream>>>(Wr, WrT, 256, 256);
    transpose_bf16<<<dim3(32, 8, 4), 256, 0, stream>>>(dense_W, denseT, 256, 1024);
    transpose_bf16<<<dim3(2, 8, 1), 256, 0, stream>>>(tail_W, tailT, 256, 64);
    convert_bf16<<<(NN * DHID / 4 + 255) / 256, 256, 0, stream>>>(x, xb, NN * DHID / 4);

    dim3 gmm((NN + 127) / 128, 2);
    // h = x @ head_W + head_b
    gemm_mfma_f32<<<gmm, 256, 0, stream>>>(xb, headT, head_b, h, NN, 256);

    for (int l = 0; l < 4; ++l) {
        ln_kernel<<<NN / 4, 256, 0, stream>>>(h, ng_g + l * 256, ng_b + l * 256, hn, hnb, NN);
        gemm_mfma_b16<<<gmm, 256, 0, stream>>>(hnb, WlT + (size_t)l * 65536, zlb, NN);
        gemm_mfma_b16<<<gmm, 256, 0, stream>>>(hnb, WrT + (size_t)l * 65536, zrb, NN);
        scores_kernel<<<(EE + 3) / 4, 256, 0, stream>>>(zlb, zrb, att + l * 256, ssrc, sdst, s, EE);
        agg_kernel<<<(NN + 3) / 4, 256, 0, stream>>>(s, ssrc, indptr, zrb, hn, h, NN);
        ln_kernel<<<NN / 4, 256, 0, stream>>>(h, nd_g + l * 256, nd_b + l * 256, hn, hnb, NN);
        dense_mfma<<<gmm, 256, 0, stream>>>(hnb, denseT + (size_t)l * 262144, dense_b + l * 1024, hn, h, xb, NN);
    }
    // out = h @ tail_W + tail_b  (xb holds bf16 of final h)
    gemm_mfma_f32<<<dim3((NN + 127) / 128, 1), 256, 0, stream>>>(xb, tailT, tail_b, out, NN, 64);
}

// Round 4
// 956.712 us; speedup vs baseline: 2.1954x; 1.3111x over previous
//
#include <hip/hip_runtime.h>
#include <cstdint>

#define NN 20000
#define EE 320000
#define DHID 256

typedef short bf16x8 __attribute__((ext_vector_type(8)));
typedef float f32x4 __attribute__((ext_vector_type(4)));

// ---------------------------------------------------------------- utilities

__device__ __forceinline__ float b2f(unsigned short u) {
    union { unsigned int i; float f; } v;
    v.i = ((unsigned int)u) << 16;
    return v.f;
}

__device__ __forceinline__ unsigned short f2b(float x) {
    union { float f; unsigned int i; } v;
    v.f = x;
    unsigned int r = (v.i + 0x7FFFu + ((v.i >> 16) & 1u)) >> 16;
    return (unsigned short)r;
}

__device__ __forceinline__ float wave_sum(float v) {
#pragma unroll
    for (int m = 1; m < 64; m <<= 1) v += __shfl_xor(v, m);
    return v;
}

__device__ __forceinline__ float gelu_f(float x) {
    float z = 0.7978845608028654f * (x + 0.044715f * x * x * x);
    float e = __expf(2.0f * z);
    float t = 1.0f - 2.0f / (e + 1.0f);   // tanh(z)
    return 0.5f * x * (1.0f + t);
}

// async global->LDS, 16B per lane; lds dest is wave-uniform base (+HW lane*16)
__device__ __forceinline__ void gld16(const unsigned short* g, unsigned short* lds) {
    __builtin_amdgcn_global_load_lds((const __attribute__((address_space(1))) unsigned int*)g,
                                     (__attribute__((address_space(3))) unsigned int*)lds, 16, 0, 0);
}

// ---------------------------------------------------------------- CSR build

__global__ void hist_kernel(const int* __restrict__ edges, int* __restrict__ counts, int E_) {
    int e = blockIdx.x * 256 + threadIdx.x;
    if (e >= E_) return;
    atomicAdd(&counts[edges[e * 2]], 1);
}

__global__ __launch_bounds__(1024) void scan_block(const int* __restrict__ counts,
                                                   int* __restrict__ excl,
                                                   int* __restrict__ bsums, int n) {
    __shared__ int sd[1024];
    int tid = threadIdx.x;
    int i = blockIdx.x * 1024 + tid;
    int c = (i < n) ? counts[i] : 0;
    sd[tid] = c;
    __syncthreads();
#pragma unroll
    for (int off = 1; off < 1024; off <<= 1) {
        int v = (tid >= off) ? sd[tid - off] : 0;
        __syncthreads();
        sd[tid] += v;
        __syncthreads();
    }
    if (i < n) excl[i] = sd[tid] - c;
    if (tid == 1023) bsums[blockIdx.x] = sd[1023];
}

__global__ void scan_tops(int* __restrict__ bsums, int nb) {
    if (threadIdx.x == 0 && blockIdx.x == 0) {
        int run = 0;
        for (int i = 0; i < nb; ++i) { int t = bsums[i]; bsums[i] = run; run += t; }
    }
}

__global__ void scan_fix(const int* __restrict__ excl, const int* __restrict__ bsums,
                         int* __restrict__ indptr, int* __restrict__ cursor, int n) {
    int i = blockIdx.x * 256 + threadIdx.x;
    if (i < n) {
        int v = excl[i] + bsums[i >> 10];
        indptr[i] = v;
        cursor[i] = v;
    }
    if (i == 0) indptr[n] = EE;
}

__global__ void scatter_kernel(const int* __restrict__ edges, int* __restrict__ cursor,
                               int* __restrict__ ssrc, int* __restrict__ sdst, int E_) {
    int e = blockIdx.x * 256 + threadIdx.x;
    if (e >= E_) return;
    int dstn = edges[e * 2];
    int src  = edges[e * 2 + 1];
    int pos = atomicAdd(&cursor[dstn], 1);
    ssrc[pos] = src;
    sdst[pos] = dstn;
}

// ---------------------------------------------------------------- weight transpose: W (K x M) fp32 -> Wt (M x K) bf16

__global__ __launch_bounds__(256) void transpose_bf16(const float* __restrict__ W,
                                                      unsigned short* __restrict__ Wt,
                                                      int K, int M, size_t lsW, size_t lsT) {
    W  += (size_t)blockIdx.z * lsW;
    Wt += (size_t)blockIdx.z * lsT;
    __shared__ float sm[32][33];
    int m0 = blockIdx.x * 32, k0 = blockIdx.y * 32;
    int tx = threadIdx.x & 31, ty = threadIdx.x >> 5;
#pragma unroll
    for (int i = 0; i < 4; ++i)
        sm[ty + i * 8][tx] = W[(size_t)(k0 + ty + i * 8) * M + m0 + tx];
    __syncthreads();
#pragma unroll
    for (int i = 0; i < 4; ++i)
        Wt[(size_t)(m0 + ty + i * 8) * K + k0 + tx] = f2b(sm[tx][ty + i * 8]);
}

__global__ void convert_bf16(const float* __restrict__ in, unsigned short* __restrict__ out, int n4) {
    int i = blockIdx.x * 256 + threadIdx.x;
    if (i >= n4) return;
    float4 v = *(const float4*)(in + (size_t)i * 4);
    ushort4 o;
    o.x = f2b(v.x); o.y = f2b(v.y); o.z = f2b(v.z); o.w = f2b(v.w);
    *(ushort4*)(out + (size_t)i * 4) = o;
}

// ---------------------------------------------------------------- LayerNorm (plain, fp32 in -> fp32 + bf16)

__global__ __launch_bounds__(256) void ln_kernel(const float* __restrict__ X,
                                                 const float* __restrict__ g,
                                                 const float* __restrict__ b,
                                                 float* __restrict__ Y,
                                                 unsigned short* __restrict__ Yb, int nrows) {
    int row = blockIdx.x * 4 + (threadIdx.x >> 6);
    int lane = threadIdx.x & 63;
    if (row >= nrows) return;
    float4 v = *(const float4*)(X + (size_t)row * DHID + lane * 4);
    float sum = wave_sum(v.x + v.y + v.z + v.w);
    float sq  = wave_sum(v.x * v.x + v.y * v.y + v.z * v.z + v.w * v.w);
    float mean = sum * (1.0f / DHID);
    float var  = sq * (1.0f / DHID) - mean * mean;
    float r = rsqrtf(fmaxf(var, 0.0f) + 1e-3f);
    float4 gv = *(const float4*)(g + lane * 4);
    float4 bv = *(const float4*)(b + lane * 4);
    float4 o;
    o.x = (v.x - mean) * r * gv.x + bv.x;
    o.y = (v.y - mean) * r * gv.y + bv.y;
    o.z = (v.z - mean) * r * gv.z + bv.z;
    o.w = (v.w - mean) * r * gv.w + bv.w;
    *(float4*)(Y + (size_t)row * DHID + lane * 4) = o;
    ushort4 ob;
    ob.x = f2b(o.x); ob.y = f2b(o.y); ob.z = f2b(o.z); ob.w = f2b(o.w);
    *(ushort4*)(Yb + (size_t)row * DHID + lane * 4) = ob;
}

// LayerNorm fused with dense-chunk-sum + residual: v = sum_c d[n][c*256+j] + xr[n][j]; LN(v)
__global__ __launch_bounds__(256) void ln_dense(const unsigned short* __restrict__ d,
                                                const float* __restrict__ xr,
                                                const float* __restrict__ g,
                                                const float* __restrict__ b,
                                                float* __restrict__ Y,
                                                unsigned short* __restrict__ Yb, int nrows) {
    int row = blockIdx.x * 4 + (threadIdx.x >> 6);
    int lane = threadIdx.x & 63;
    if (row >= nrows) return;
    float4 v = *(const float4*)(xr + (size_t)row * DHID + lane * 4);
#pragma unroll
    for (int c = 0; c < 4; ++c) {
        ushort4 t = *(const ushort4*)(d + (size_t)row * 1024 + c * 256 + lane * 4);
        v.x += b2f(t.x); v.y += b2f(t.y); v.z += b2f(t.z); v.w += b2f(t.w);
    }
    float sum = wave_sum(v.x + v.y + v.z + v.w);
    float sq  = wave_sum(v.x * v.x + v.y * v.y + v.z * v.z + v.w * v.w);
    float mean = sum * (1.0f / DHID);
    float var  = sq * (1.0f / DHID) - mean * mean;
    float r = rsqrtf(fmaxf(var, 0.0f) + 1e-3f);
    float4 gv = *(const float4*)(g + lane * 4);
    float4 bv = *(const float4*)(b + lane * 4);
    float4 o;
    o.x = (v.x - mean) * r * gv.x + bv.x;
    o.y = (v.y - mean) * r * gv.y + bv.y;
    o.z = (v.z - mean) * r * gv.z + bv.z;
    o.w = (v.w - mean) * r * gv.w + bv.w;
    *(float4*)(Y + (size_t)row * DHID + lane * 4) = o;
    ushort4 ob;
    ob.x = f2b(o.x); ob.y = f2b(o.y); ob.z = f2b(o.z); ob.w = f2b(o.w);
    *(ushort4*)(Yb + (size_t)row * DHID + lane * 4) = ob;
}

// final combine (no LN): hb = bf16(sum_c d + xr)
__global__ __launch_bounds__(256) void combine_final(const unsigned short* __restrict__ d,
                                                     const float* __restrict__ xr,
                                                     unsigned short* __restrict__ hb, int nrows) {
    int row = blockIdx.x * 4 + (threadIdx.x >> 6);
    int lane = threadIdx.x & 63;
    if (row >= nrows) return;
    float4 v = *(const float4*)(xr + (size_t)row * DHID + lane * 4);
#pragma unroll
    for (int c = 0; c < 4; ++c) {
        ushort4 t = *(const ushort4*)(d + (size_t)row * 1024 + c * 256 + lane * 4);
        v.x += b2f(t.x); v.y += b2f(t.y); v.z += b2f(t.z); v.w += b2f(t.w);
    }
    ushort4 ob;
    ob.x = f2b(v.x); ob.y = f2b(v.y); ob.z = f2b(v.z); ob.w = f2b(v.w);
    *(ushort4*)(hb + (size_t)row * DHID + lane * 4) = ob;
}

// ---------------------------------------------------------------- MFMA GEMM, 128x128 tile, LDS-staged (m97 style)
// A: nrows x 256 bf16 (k contig); B: ncols x 256 bf16 (k contig, i.e. W^T)
// EP: 0 = fp32 out (+bias), 1 = bf16 out, 2 = bf16 gelu(acc + bias)

template <int EP>
__global__ __launch_bounds__(256, 3) void gemm128(const unsigned short* __restrict__ A,
                                                  const unsigned short* __restrict__ B,
                                                  const float* __restrict__ bias,
                                                  void* __restrict__ Cv, int nrows, int ncols) {
    // LDS layout: rowgroup (16 rows) blocks of 512 shorts:
    //   offset(row,g) = (row>>4)*512 + g*128 + (row&15)*8   (g = k-group of 8 bf16)
    __shared__ unsigned short As[128 * 32];
    __shared__ unsigned short Bs[128 * 32];
    const int tid  = threadIdx.x;
    const int w    = tid >> 6, lane = tid & 63;
    const int quad = lane >> 4, l16 = lane & 15;
    const int wm = w >> 1, wn = w & 1;
    const int bm = blockIdx.x * 128, bn = blockIdx.y * 128;

    const int srow = lane & 15;
    const int sg   = lane >> 4;
    int ga0 = min(bm + w * 32 + srow,      nrows - 1);
    int ga1 = min(bm + w * 32 + 16 + srow, nrows - 1);
    int gb0 = min(bn + w * 32 + srow,      ncols - 1);
    int gb1 = min(bn + w * 32 + 16 + srow, ncols - 1);
    const unsigned short* Ap0 = A + (size_t)ga0 * 256 + sg * 8;
    const unsigned short* Ap1 = A + (size_t)ga1 * 256 + sg * 8;
    const unsigned short* Bp0 = B + (size_t)gb0 * 256 + sg * 8;
    const unsigned short* Bp1 = B + (size_t)gb1 * 256 + sg * 8;
    unsigned short* la0 = As + (2 * w) * 512;
    unsigned short* la1 = As + (2 * w + 1) * 512;
    unsigned short* lb0 = Bs + (2 * w) * 512;
    unsigned short* lb1 = Bs + (2 * w + 1) * 512;

    f32x4 acc[4][4] = {};
    for (int k0 = 0; k0 < 256; k0 += 32) {
        gld16(Ap0 + k0, la0);
        gld16(Ap1 + k0, la1);
        gld16(Bp0 + k0, lb0);
        gld16(Bp1 + k0, lb1);
        __syncthreads();
        bf16x8 a[4], b[4];
#pragma unroll
        for (int mi = 0; mi < 4; ++mi)
            a[mi] = *(const bf16x8*)(As + (wm * 4 + mi) * 512 + quad * 128 + l16 * 8);
#pragma unroll
        for (int ni = 0; ni < 4; ++ni)
            b[ni] = *(const bf16x8*)(Bs + (wn * 4 + ni) * 512 + quad * 128 + l16 * 8);
#pragma unroll
        for (int mi = 0; mi < 4; ++mi)
#pragma unroll
            for (int ni = 0; ni < 4; ++ni)
                acc[mi][ni] = __builtin_amdgcn_mfma_f32_16x16x32_bf16(a[mi], b[ni], acc[mi][ni], 0, 0, 0);
        __syncthreads();
    }

#pragma unroll
    for (int ni = 0; ni < 4; ++ni) {
        int col = bn + wn * 64 + ni * 16 + l16;
        if (col >= ncols) continue;
        float bv = (EP != 1 && bias) ? bias[col] : 0.0f;
#pragma unroll
        for (int mi = 0; mi < 4; ++mi) {
#pragma unroll
            for (int r = 0; r < 4; ++r) {
                int row = bm + wm * 64 + mi * 16 + quad * 4 + r;
                if (row >= nrows) continue;
                float v = acc[mi][ni][r] + bv;
                if (EP == 0) ((float*)Cv)[(size_t)row * ncols + col] = v;
                else if (EP == 1) ((unsigned short*)Cv)[(size_t)row * ncols + col] = f2b(v);
                else ((unsigned short*)Cv)[(size_t)row * ncols + col] = f2b(gelu_f(v));
            }
        }
    }
}

// ---------------------------------------------------------------- edge scores: zb stacked [n][512] = [zl | zr]

__global__ __launch_bounds__(256) void scores_kernel(const unsigned short* __restrict__ zb,
                                                     const float* __restrict__ att,
                                                     const int* __restrict__ ssrc,
                                                     const int* __restrict__ sdst,
                                                     float* __restrict__ s, int E_) {
    int wid = threadIdx.x >> 6;
    int lane = threadIdx.x & 63;
    int quad = lane >> 4, l16 = lane & 15;
    int p = blockIdx.x * 4 + wid;
    if (p >= E_) return;
    int src = ssrc[p];
    int dstn = sdst[p];
    float4 a4 = *(const float4*)(att + lane * 4);
    ushort4 lv = *(const ushort4*)(zb + (size_t)dstn * 512 + lane * 4);
    ushort4 rv = *(const ushort4*)(zb + (size_t)src * 512 + 256 + lane * 4);
    float v0 = b2f(lv.x) + b2f(rv.x);
    float v1 = b2f(lv.y) + b2f(rv.y);
    float v2 = b2f(lv.z) + b2f(rv.z);
    float v3 = b2f(lv.w) + b2f(rv.w);
    v0 = (v0 > 0.f) ? v0 : 0.2f * v0;
    v1 = (v1 > 0.f) ? v1 : 0.2f * v1;
    v2 = (v2 > 0.f) ? v2 : 0.2f * v2;
    v3 = (v3 > 0.f) ? v3 : 0.2f * v3;
    float sum = a4.x * v0 + a4.y * v1 + a4.z * v2 + a4.w * v3;
#pragma unroll
    for (int m = 1; m < 16; m <<= 1) sum += __shfl_xor(sum, m);
    if (l16 == 0) s[p * 4 + quad] = sum;
}

// ---------------------------------------------------------------- per-node softmax + agg + residual + LayerNorm (fused)

__global__ __launch_bounds__(256) void agg_ln(const float* __restrict__ s,
                                              const int* __restrict__ ssrc,
                                              const int* __restrict__ indptr,
                                              const unsigned short* __restrict__ zb,
                                              const float* __restrict__ hn,
                                              const float* __restrict__ g,
                                              const float* __restrict__ b,
                                              float* __restrict__ xr,
                                              unsigned short* __restrict__ xrb, int nrows) {
    int wid = threadIdx.x >> 6;
    int lane = threadIdx.x & 63;
    int quad = lane >> 4, l16 = lane & 15;
    int n = blockIdx.x * 4 + wid;
    if (n >= nrows) return;
    int start = indptr[n];
    int end = indptr[n + 1];
    float m = -3.0e38f;
    for (int p = start + l16; p < end; p += 16) m = fmaxf(m, s[p * 4 + quad]);
#pragma unroll
    for (int mm = 1; mm < 16; mm <<= 1) m = fmaxf(m, __shfl_xor(m, mm));
    float denom = 0.f;
    float ax = 0.f, ay = 0.f, az = 0.f, aw = 0.f;
    for (int p = start; p < end; ++p) {
        float es = __expf(s[p * 4 + quad] - m);
        denom += es;
        int src = ssrc[p];
        ushort4 v = *(const ushort4*)(zb + (size_t)src * 512 + 256 + lane * 4);
        ax += es * b2f(v.x);
        ay += es * b2f(v.y);
        az += es * b2f(v.z);
        aw += es * b2f(v.w);
    }
    float inv = 1.0f / (denom + 1e-9f);
    size_t idx = (size_t)n * DHID + lane * 4;
    float4 r = *(const float4*)(hn + idx);
    float4 o;
    o.x = ax * inv + r.x;
    o.y = ay * inv + r.y;
    o.z = az * inv + r.z;
    o.w = aw * inv + r.w;
    float sum = wave_sum(o.x + o.y + o.z + o.w);
    float sq  = wave_sum(o.x * o.x + o.y * o.y + o.z * o.z + o.w * o.w);
    float mean = sum * (1.0f / DHID);
    float var  = sq * (1.0f / DHID) - mean * mean;
    float rr = rsqrtf(fmaxf(var, 0.0f) + 1e-3f);
    float4 gv = *(const float4*)(g + lane * 4);
    float4 bv = *(const float4*)(b + lane * 4);
    float4 y;
    y.x = (o.x - mean) * rr * gv.x + bv.x;
    y.y = (o.y - mean) * rr * gv.y + bv.y;
    y.z = (o.z - mean) * rr * gv.z + bv.z;
    y.w = (o.w - mean) * rr * gv.w + bv.w;
    *(float4*)(xr + idx) = y;
    ushort4 ob;
    ob.x = f2b(y.x); ob.y = f2b(y.y); ob.z = f2b(y.z); ob.w = f2b(y.w);
    *(ushort4*)(xrb + idx) = ob;
}

// ---------------------------------------------------------------- host

extern "C" void kernel_launch(void* const* d_in, const int* in_sizes, int n_in,
                              void* d_out, int out_size, void* d_ws, size_t ws_size,
                              hipStream_t stream) {
    const float* x       = (const float*)d_in[0];
    const float* head_W  = (const float*)d_in[1];
    const float* head_b  = (const float*)d_in[2];
    const float* ng_g    = (const float*)d_in[3];
    const float* ng_b    = (const float*)d_in[4];
    const float* Wl      = (const float*)d_in[5];
    const float* Wr      = (const float*)d_in[6];
    const float* att     = (const float*)d_in[7];
    const float* nd_g    = (const float*)d_in[8];
    const float* nd_b    = (const float*)d_in[9];
    const float* dense_W = (const float*)d_in[10];
    const float* dense_b = (const float*)d_in[11];
    const float* tail_W  = (const float*)d_in[12];
    const float* tail_b  = (const float*)d_in[13];
    const int*   edges   = (const int*)d_in[14];
    float* out = (float*)d_out;

    const size_t NH = (size_t)NN * DHID;  // 5,120,000
    // ---- workspace layout (liveness-checked; d/zb/s union is deliberate) ----
    float* xr = (float*)d_ws;                           // NH f32  (head-out, then agg_ln out)
    float* hn = xr + NH;                                // NH f32  (LN out, GAT residual)
    unsigned short* hnb = (unsigned short*)(hn + NH);   // NH bf16 (x-bf16, then LN-out bf16, then final hb)
    unsigned short* xrb = hnb + NH;                     // NH bf16
    unsigned short* U   = xrb + NH;                     // union region, 4*NH shorts (40.96 MB)
    unsigned short* zb  = U;                            //   N x 512 bf16   (dies at agg_ln)
    float*          s   = (float*)(U + 2 * NH);         //   E x 4 f32      (dies at agg_ln)
    unsigned short* d_buf = U;                          //   N x 1024 bf16  (written after agg_ln, dies at ln_dense)
    unsigned short* headT  = U + 4 * NH;
    unsigned short* WzT    = headT + 65536;             // 4 x (512 x 256)
    unsigned short* denseT = WzT + 524288;              // 4 x (1024 x 256)
    unsigned short* tailT  = denseT + 1048576;          // 64 x 256
    int* counts = (int*)(tailT + 16384);
    int* bsums  = counts + NN;
    int* excl   = bsums + 32;
    int* indptr = excl + NN;
    int* cursor = indptr + NN + 1;
    int* ssrc   = cursor + NN;
    int* sdst   = ssrc + EE;

    // CSR build
    hipMemsetAsync(counts, 0, NN * sizeof(int), stream);
    hist_kernel<<<(EE + 255) / 256, 256, 0, stream>>>(edges, counts, EE);
    scan_block<<<(NN + 1023) / 1024, 1024, 0, stream>>>(counts, excl, bsums, NN);
    scan_tops<<<1, 64, 0, stream>>>(bsums, (NN + 1023) / 1024);
    scan_fix<<<(NN + 255) / 256, 256, 0, stream>>>(excl, bsums, indptr, cursor, NN);
    scatter_kernel<<<(EE + 255) / 256, 256, 0, stream>>>(edges, cursor, ssrc, sdst, EE);

    // weight prep
    transpose_bf16<<<dim3(8, 8, 1), 256, 0, stream>>>(head_W, headT, 256, 256, 0, 0);
    transpose_bf16<<<dim3(8, 8, 4), 256, 0, stream>>>(Wl, WzT, 256, 256, 65536, 131072);
    transpose_bf16<<<dim3(8, 8, 4), 256, 0, stream>>>(Wr, WzT + 65536, 256, 256, 65536, 131072);
    transpose_bf16<<<dim3(32, 8, 4), 256, 0, stream>>>(dense_W, denseT, 256, 1024, 262144, 262144);
    transpose_bf16<<<dim3(2, 8, 1), 256, 0, stream>>>(tail_W, tailT, 256, 64, 0, 0);
    // bf16(x) -> hnb (dead region at this point)
    convert_bf16<<<(int)(NH / 4 + 255) / 256, 256, 0, stream>>>(x, hnb, (int)(NH / 4));

    const int GX = (NN + 127) / 128;  // 157
    // head: xr = x @ head_W + head_b (fp32)
    gemm128<0><<<dim3(GX, 2), 256, 0, stream>>>(hnb, headT, head_b, xr, NN, 256);

    for (int l = 0; l < 4; ++l) {
        if (l == 0)
            ln_kernel<<<NN / 4, 256, 0, stream>>>(xr, ng_g, ng_b, hn, hnb, NN);
        else
            ln_dense<<<NN / 4, 256, 0, stream>>>(d_buf, xr, ng_g + l * 256, ng_b + l * 256, hn, hnb, NN);
        // [zl|zr] = hn @ [Wl|Wr]
        gemm128<1><<<dim3(GX, 4), 256, 0, stream>>>(hnb, WzT + (size_t)l * 131072, nullptr, zb, NN, 512);
        scores_kernel<<<(EE + 3) / 4, 256, 0, stream>>>(zb, att + l * 256, ssrc, sdst, s, EE);
        agg_ln<<<(NN + 3) / 4, 256, 0, stream>>>(s, ssrc, indptr, zb, hn,
                                                 nd_g + l * 256, nd_b + l * 256, xr, xrb, NN);
        // d = gelu(xr @ dense_W + dense_b)  (partial chunks, bf16) — clobbers zb/s (both dead)
        gemm128<2><<<dim3(GX, 8), 256, 0, stream>>>(xrb, denseT + (size_t)l * 262144,
                                                    dense_b + l * 1024, d_buf, NN, 1024);
    }
    // hb = bf16(sum_c d + xr) -> hnb (dead); out = hb @ tail_W + tail_b
    combine_final<<<NN / 4, 256, 0, stream>>>(d_buf, xr, hnb, NN);
    gemm128<0><<<dim3(GX, 1), 256, 0, stream>>>(hnb, tailT, tail_b, out, NN, 64);
}

// Round 6
// 746.400 us; speedup vs baseline: 2.8140x; 1.2818x over previous
//
#include <hip/hip_runtime.h>
#include <cstdint>

#define NN 20000
#define EE 320000
#define DHID 256

typedef short bf16x8 __attribute__((ext_vector_type(8)));
typedef float f32x4 __attribute__((ext_vector_type(4)));

// ---------------------------------------------------------------- utilities

__device__ __forceinline__ float b2f(unsigned short u) {
    union { unsigned int i; float f; } v;
    v.i = ((unsigned int)u) << 16;
    return v.f;
}

__device__ __forceinline__ unsigned short f2b(float x) {
    union { float f; unsigned int i; } v;
    v.f = x;
    unsigned int r = (v.i + 0x7FFFu + ((v.i >> 16) & 1u)) >> 16;
    return (unsigned short)r;
}

__device__ __forceinline__ float wave_sum(float v) {
#pragma unroll
    for (int m = 1; m < 64; m <<= 1) v += __shfl_xor(v, m);
    return v;
}

__device__ __forceinline__ float quad16_sum(float v) {
#pragma unroll
    for (int m = 1; m < 16; m <<= 1) v += __shfl_xor(v, m);
    return v;
}

__device__ __forceinline__ float gelu_f(float x) {
    float z = 0.7978845608028654f * (x + 0.044715f * x * x * x);
    float e = __expf(2.0f * z);
    float t = 1.0f - 2.0f / (e + 1.0f);   // tanh(z)
    return 0.5f * x * (1.0f + t);
}

// async global->LDS, 16B per lane; lds dest is wave-uniform base (+HW lane*16)
__device__ __forceinline__ void gld16(const unsigned short* g, unsigned short* lds) {
    __builtin_amdgcn_global_load_lds((const __attribute__((address_space(1))) unsigned int*)g,
                                     (__attribute__((address_space(3))) unsigned int*)lds, 16, 0, 0);
}

// ---------------------------------------------------------------- CSR build

__global__ void hist_kernel(const int* __restrict__ edges, int* __restrict__ counts, int E_) {
    int e = blockIdx.x * 256 + threadIdx.x;
    if (e >= E_) return;
    atomicAdd(&counts[edges[e * 2]], 1);
}

__global__ __launch_bounds__(1024) void scan_block(const int* __restrict__ counts,
                                                   int* __restrict__ excl,
                                                   int* __restrict__ bsums, int n) {
    __shared__ int sd[1024];
    int tid = threadIdx.x;
    int i = blockIdx.x * 1024 + tid;
    int c = (i < n) ? counts[i] : 0;
    sd[tid] = c;
    __syncthreads();
#pragma unroll
    for (int off = 1; off < 1024; off <<= 1) {
        int v = (tid >= off) ? sd[tid - off] : 0;
        __syncthreads();
        sd[tid] += v;
        __syncthreads();
    }
    if (i < n) excl[i] = sd[tid] - c;
    if (tid == 1023) bsums[blockIdx.x] = sd[1023];
}

__global__ void scan_tops(int* __restrict__ bsums, int nb) {
    if (threadIdx.x == 0 && blockIdx.x == 0) {
        int run = 0;
        for (int i = 0; i < nb; ++i) { int t = bsums[i]; bsums[i] = run; run += t; }
    }
}

__global__ void scan_fix(const int* __restrict__ excl, const int* __restrict__ bsums,
                         int* __restrict__ indptr, int* __restrict__ cursor, int n) {
    int i = blockIdx.x * 256 + threadIdx.x;
    if (i < n) {
        int v = excl[i] + bsums[i >> 10];
        indptr[i] = v;
        cursor[i] = v;
    }
    if (i == 0) indptr[n] = EE;
}

__global__ void scatter_kernel(const int* __restrict__ edges, int* __restrict__ cursor,
                               int* __restrict__ ssrc, int E_) {
    int e = blockIdx.x * 256 + threadIdx.x;
    if (e >= E_) return;
    int dstn = edges[e * 2];
    int src  = edges[e * 2 + 1];
    int pos = atomicAdd(&cursor[dstn], 1);
    ssrc[pos] = src;
}

// ---------------------------------------------------------------- weight transpose: W (K x M) fp32 -> Wt (M x K) bf16

__global__ __launch_bounds__(256) void transpose_bf16(const float* __restrict__ W,
                                                      unsigned short* __restrict__ Wt,
                                                      int K, int M, size_t lsW, size_t lsT) {
    W  += (size_t)blockIdx.z * lsW;
    Wt += (size_t)blockIdx.z * lsT;
    __shared__ float sm[32][33];
    int m0 = blockIdx.x * 32, k0 = blockIdx.y * 32;
    int tx = threadIdx.x & 31, ty = threadIdx.x >> 5;
#pragma unroll
    for (int i = 0; i < 4; ++i)
        sm[ty + i * 8][tx] = W[(size_t)(k0 + ty + i * 8) * M + m0 + tx];
    __syncthreads();
#pragma unroll
    for (int i = 0; i < 4; ++i)
        Wt[(size_t)(m0 + ty + i * 8) * K + k0 + tx] = f2b(sm[tx][ty + i * 8]);
}

__global__ void convert_bf16(const float* __restrict__ in, unsigned short* __restrict__ out, int n4) {
    int i = blockIdx.x * 256 + threadIdx.x;
    if (i >= n4) return;
    float4 v = *(const float4*)(in + (size_t)i * 4);
    ushort4 o;
    o.x = f2b(v.x); o.y = f2b(v.y); o.z = f2b(v.z); o.w = f2b(v.w);
    *(ushort4*)(out + (size_t)i * 4) = o;
}

// ---------------------------------------------------------------- LayerNorm (plain, fp32 in -> fp32 + bf16)

__global__ __launch_bounds__(256) void ln_kernel(const float* __restrict__ X,
                                                 const float* __restrict__ g,
                                                 const float* __restrict__ b,
                                                 float* __restrict__ Y,
                                                 unsigned short* __restrict__ Yb, int nrows) {
    int row = blockIdx.x * 4 + (threadIdx.x >> 6);
    int lane = threadIdx.x & 63;
    if (row >= nrows) return;
    float4 v = *(const float4*)(X + (size_t)row * DHID + lane * 4);
    float sum = wave_sum(v.x + v.y + v.z + v.w);
    float sq  = wave_sum(v.x * v.x + v.y * v.y + v.z * v.z + v.w * v.w);
    float mean = sum * (1.0f / DHID);
    float var  = sq * (1.0f / DHID) - mean * mean;
    float r = rsqrtf(fmaxf(var, 0.0f) + 1e-3f);
    float4 gv = *(const float4*)(g + lane * 4);
    float4 bv = *(const float4*)(b + lane * 4);
    float4 o;
    o.x = (v.x - mean) * r * gv.x + bv.x;
    o.y = (v.y - mean) * r * gv.y + bv.y;
    o.z = (v.z - mean) * r * gv.z + bv.z;
    o.w = (v.w - mean) * r * gv.w + bv.w;
    *(float4*)(Y + (size_t)row * DHID + lane * 4) = o;
    ushort4 ob;
    ob.x = f2b(o.x); ob.y = f2b(o.y); ob.z = f2b(o.z); ob.w = f2b(o.w);
    *(ushort4*)(Yb + (size_t)row * DHID + lane * 4) = ob;
}

// LayerNorm fused with dense-chunk-sum + residual: v = sum_c d[n][c*256+j] + xr[n][j]; LN(v)
__global__ __launch_bounds__(256) void ln_dense(const unsigned short* __restrict__ d,
                                                const float* __restrict__ xr,
                                                const float* __restrict__ g,
                                                const float* __restrict__ b,
                                                float* __restrict__ Y,
                                                unsigned short* __restrict__ Yb, int nrows) {
    int row = blockIdx.x * 4 + (threadIdx.x >> 6);
    int lane = threadIdx.x & 63;
    if (row >= nrows) return;
    float4 v = *(const float4*)(xr + (size_t)row * DHID + lane * 4);
#pragma unroll
    for (int c = 0; c < 4; ++c) {
        ushort4 t = *(const ushort4*)(d + (size_t)row * 1024 + c * 256 + lane * 4);
        v.x += b2f(t.x); v.y += b2f(t.y); v.z += b2f(t.z); v.w += b2f(t.w);
    }
    float sum = wave_sum(v.x + v.y + v.z + v.w);
    float sq  = wave_sum(v.x * v.x + v.y * v.y + v.z * v.z + v.w * v.w);
    float mean = sum * (1.0f / DHID);
    float var  = sq * (1.0f / DHID) - mean * mean;
    float r = rsqrtf(fmaxf(var, 0.0f) + 1e-3f);
    float4 gv = *(const float4*)(g + lane * 4);
    float4 bv = *(const float4*)(b + lane * 4);
    float4 o;
    o.x = (v.x - mean) * r * gv.x + bv.x;
    o.y = (v.y - mean) * r * gv.y + bv.y;
    o.z = (v.z - mean) * r * gv.z + bv.z;
    o.w = (v.w - mean) * r * gv.w + bv.w;
    *(float4*)(Y + (size_t)row * DHID + lane * 4) = o;
    ushort4 ob;
    ob.x = f2b(o.x); ob.y = f2b(o.y); ob.z = f2b(o.z); ob.w = f2b(o.w);
    *(ushort4*)(Yb + (size_t)row * DHID + lane * 4) = ob;
}

// final combine (no LN): hb = bf16(sum_c d + xr)
__global__ __launch_bounds__(256) void combine_final(const unsigned short* __restrict__ d,
                                                     const float* __restrict__ xr,
                                                     unsigned short* __restrict__ hb, int nrows) {
    int row = blockIdx.x * 4 + (threadIdx.x >> 6);
    int lane = threadIdx.x & 63;
    if (row >= nrows) return;
    float4 v = *(const float4*)(xr + (size_t)row * DHID + lane * 4);
#pragma unroll
    for (int c = 0; c < 4; ++c) {
        ushort4 t = *(const ushort4*)(d + (size_t)row * 1024 + c * 256 + lane * 4);
        v.x += b2f(t.x); v.y += b2f(t.y); v.z += b2f(t.z); v.w += b2f(t.w);
    }
    ushort4 ob;
    ob.x = f2b(v.x); ob.y = f2b(v.y); ob.z = f2b(v.z); ob.w = f2b(v.w);
    *(ushort4*)(hb + (size_t)row * DHID + lane * 4) = ob;
}

// ---------------------------------------------------------------- MFMA GEMM, 128x128 tile, LDS-staged (m97 style)
// A: nrows x 256 bf16 (k contig); B: ncols x 256 bf16 (k contig, i.e. W^T)
// EP: 0 = fp32 out (+bias), 1 = bf16 out, 2 = bf16 gelu(acc + bias)

template <int EP>
__global__ __launch_bounds__(256, 3) void gemm128(const unsigned short* __restrict__ A,
                                                  const unsigned short* __restrict__ B,
                                                  const float* __restrict__ bias,
                                                  void* __restrict__ Cv, int nrows, int ncols) {
    // LDS layout: rowgroup (16 rows) blocks of 512 shorts:
    //   offset(row,g) = (row>>4)*512 + g*128 + (row&15)*8   (g = k-group of 8 bf16)
    __shared__ unsigned short As[128 * 32];
    __shared__ unsigned short Bs[128 * 32];
    const int tid  = threadIdx.x;
    const int w    = tid >> 6, lane = tid & 63;
    const int quad = lane >> 4, l16 = lane & 15;
    const int wm = w >> 1, wn = w & 1;
    const int bm = blockIdx.x * 128, bn = blockIdx.y * 128;

    const int srow = lane & 15;
    const int sg   = lane >> 4;
    int ga0 = min(bm + w * 32 + srow,      nrows - 1);
    int ga1 = min(bm + w * 32 + 16 + srow, nrows - 1);
    int gb0 = min(bn + w * 32 + srow,      ncols - 1);
    int gb1 = min(bn + w * 32 + 16 + srow, ncols - 1);
    const unsigned short* Ap0 = A + (size_t)ga0 * 256 + sg * 8;
    const unsigned short* Ap1 = A + (size_t)ga1 * 256 + sg * 8;
    const unsigned short* Bp0 = B + (size_t)gb0 * 256 + sg * 8;
    const unsigned short* Bp1 = B + (size_t)gb1 * 256 + sg * 8;
    unsigned short* la0 = As + (2 * w) * 512;
    unsigned short* la1 = As + (2 * w + 1) * 512;
    unsigned short* lb0 = Bs + (2 * w) * 512;
    unsigned short* lb1 = Bs + (2 * w + 1) * 512;

    f32x4 acc[4][4] = {};
    for (int k0 = 0; k0 < 256; k0 += 32) {
        gld16(Ap0 + k0, la0);
        gld16(Ap1 + k0, la1);
        gld16(Bp0 + k0, lb0);
        gld16(Bp1 + k0, lb1);
        __syncthreads();
        bf16x8 a[4], b[4];
#pragma unroll
        for (int mi = 0; mi < 4; ++mi)
            a[mi] = *(const bf16x8*)(As + (wm * 4 + mi) * 512 + quad * 128 + l16 * 8);
#pragma unroll
        for (int ni = 0; ni < 4; ++ni)
            b[ni] = *(const bf16x8*)(Bs + (wn * 4 + ni) * 512 + quad * 128 + l16 * 8);
#pragma unroll
        for (int mi = 0; mi < 4; ++mi)
#pragma unroll
            for (int ni = 0; ni < 4; ++ni)
                acc[mi][ni] = __builtin_amdgcn_mfma_f32_16x16x32_bf16(a[mi], b[ni], acc[mi][ni], 0, 0, 0);
        __syncthreads();
    }

#pragma unroll
    for (int ni = 0; ni < 4; ++ni) {
        int col = bn + wn * 64 + ni * 16 + l16;
        if (col >= ncols) continue;
        float bv = (EP != 1 && bias) ? bias[col] : 0.0f;
#pragma unroll
        for (int mi = 0; mi < 4; ++mi) {
#pragma unroll
            for (int r = 0; r < 4; ++r) {
                int row = bm + wm * 64 + mi * 16 + quad * 4 + r;
                if (row >= nrows) continue;
                float v = acc[mi][ni][r] + bv;
                if (EP == 0) ((float*)Cv)[(size_t)row * ncols + col] = v;
                else if (EP == 1) ((unsigned short*)Cv)[(size_t)row * ncols + col] = f2b(v);
                else ((unsigned short*)Cv)[(size_t)row * ncols + col] = f2b(gelu_f(v));
            }
        }
    }
}

// ---------------------------------------------------------------- fused GAT edge phase: online-softmax scores+agg+residual+LN
// zb stacked rows [n][512] = [zl | zr]. One wave per node; head h = quad
// (lanes 16h..16h+15 hold features h*64..h*64+63, 4 per lane).
// Score reduction is PER-QUAD (16 lanes) — per-head, not whole-wave.

__global__ __launch_bounds__(256) void gat_fused(const unsigned short* __restrict__ zb,
                                                 const float* __restrict__ att,
                                                 const int* __restrict__ ssrc,
                                                 const int* __restrict__ indptr,
                                                 const float* __restrict__ hn,
                                                 const float* __restrict__ g,
                                                 const float* __restrict__ b,
                                                 float* __restrict__ xr,
                                                 unsigned short* __restrict__ xrb, int nrows) {
    int wid = threadIdx.x >> 6;
    int lane = threadIdx.x & 63;
    int n = blockIdx.x * 4 + wid;
    if (n >= nrows) return;
    int start = indptr[n];
    int end = indptr[n + 1];

    ushort4 zlu = *(const ushort4*)(zb + (size_t)n * 512 + lane * 4);
    float zl0 = b2f(zlu.x), zl1 = b2f(zlu.y), zl2 = b2f(zlu.z), zl3 = b2f(zlu.w);
    float4 a4 = *(const float4*)(att + lane * 4);

    // per-quad (= per-head) online-softmax state
    float m = -3.0e38f, denom = 0.f;
    float ax = 0.f, ay = 0.f, az = 0.f, aw = 0.f;

    ushort4 znext = make_ushort4(0, 0, 0, 0);
    if (start < end) {
        int s0 = ssrc[start];
        znext = *(const ushort4*)(zb + (size_t)s0 * 512 + 256 + lane * 4);
    }
    for (int p = start; p < end; ++p) {
        ushort4 zu = znext;
        if (p + 1 < end) {
            int s1 = ssrc[p + 1];
            znext = *(const ushort4*)(zb + (size_t)s1 * 512 + 256 + lane * 4);
        }
        float z0 = b2f(zu.x), z1 = b2f(zu.y), z2 = b2f(zu.z), z3 = b2f(zu.w);
        float v0 = zl0 + z0, v1 = zl1 + z1, v2 = zl2 + z2, v3 = zl3 + z3;
        v0 = (v0 > 0.f) ? v0 : 0.2f * v0;
        v1 = (v1 > 0.f) ? v1 : 0.2f * v1;
        v2 = (v2 > 0.f) ? v2 : 0.2f * v2;
        v3 = (v3 > 0.f) ? v3 : 0.2f * v3;
        float part = a4.x * v0 + a4.y * v1 + a4.z * v2 + a4.w * v3;
        float sp = quad16_sum(part);        // per-head score (16 lanes of this quad)
        float newm = fmaxf(m, sp);
        float corr = __expf(m - newm);      // 0 on first edge (m=-3e38)
        float w = __expf(sp - newm);
        denom = denom * corr + w;
        ax = ax * corr + w * z0;
        ay = ay * corr + w * z1;
        az = az * corr + w * z2;
        aw = aw * corr + w * z3;
        m = newm;
    }
    float inv = 1.0f / (denom + 1e-9f);
    size_t idx = (size_t)n * DHID + lane * 4;
    float4 r = *(const float4*)(hn + idx);
    float4 o;
    o.x = ax * inv + r.x;
    o.y = ay * inv + r.y;
    o.z = az * inv + r.z;
    o.w = aw * inv + r.w;
    // fused LayerNorm (full 64-lane row reduction)
    float sum = wave_sum(o.x + o.y + o.z + o.w);
    float sq  = wave_sum(o.x * o.x + o.y * o.y + o.z * o.z + o.w * o.w);
    float mean = sum * (1.0f / DHID);
    float var  = sq * (1.0f / DHID) - mean * mean;
    float rr = rsqrtf(fmaxf(var, 0.0f) + 1e-3f);
    float4 gv = *(const float4*)(g + lane * 4);
    float4 bv = *(const float4*)(b + lane * 4);
    float4 y;
    y.x = (o.x - mean) * rr * gv.x + bv.x;
    y.y = (o.y - mean) * rr * gv.y + bv.y;
    y.z = (o.z - mean) * rr * gv.z + bv.z;
    y.w = (o.w - mean) * rr * gv.w + bv.w;
    *(float4*)(xr + idx) = y;
    ushort4 ob;
    ob.x = f2b(y.x); ob.y = f2b(y.y); ob.z = f2b(y.z); ob.w = f2b(y.w);
    *(ushort4*)(xrb + idx) = ob;
}

// ---------------------------------------------------------------- host

extern "C" void kernel_launch(void* const* d_in, const int* in_sizes, int n_in,
                              void* d_out, int out_size, void* d_ws, size_t ws_size,
                              hipStream_t stream) {
    const float* x       = (const float*)d_in[0];
    const float* head_W  = (const float*)d_in[1];
    const float* head_b  = (const float*)d_in[2];
    const float* ng_g    = (const float*)d_in[3];
    const float* ng_b    = (const float*)d_in[4];
    const float* Wl      = (const float*)d_in[5];
    const float* Wr      = (const float*)d_in[6];
    const float* att     = (const float*)d_in[7];
    const float* nd_g    = (const float*)d_in[8];
    const float* nd_b    = (const float*)d_in[9];
    const float* dense_W = (const float*)d_in[10];
    const float* dense_b = (const float*)d_in[11];
    const float* tail_W  = (const float*)d_in[12];
    const float* tail_b  = (const float*)d_in[13];
    const int*   edges   = (const int*)d_in[14];
    float* out = (float*)d_out;

    const size_t NH = (size_t)NN * DHID;  // 5,120,000
    // ---- workspace layout (liveness-checked; zb/d union is deliberate) ----
    float* xr = (float*)d_ws;                           // NH f32  (head-out, then agg out)
    float* hn = xr + NH;                                // NH f32  (LN out, GAT residual)
    unsigned short* hnb = (unsigned short*)(hn + NH);   // NH bf16 (x-bf16 / LN-out bf16 / final hb)
    unsigned short* xrb = hnb + NH;                     // NH bf16
    unsigned short* U   = xrb + NH;                     // union region, 4*NH shorts (40.96 MB)
    unsigned short* zb  = U;                            //   N x 512 bf16   (dies at gat_fused)
    unsigned short* d_buf = U;                          //   N x 1024 bf16  (written after gat_fused, dies at ln_dense)
    unsigned short* headT  = U + 4 * NH;
    unsigned short* WzT    = headT + 65536;             // 4 x (512 x 256)
    unsigned short* denseT = WzT + 524288;              // 4 x (1024 x 256)
    unsigned short* tailT  = denseT + 1048576;          // 64 x 256
    int* counts = (int*)(tailT + 16384);
    int* bsums  = counts + NN;
    int* excl   = bsums + 32;
    int* indptr = excl + NN;
    int* cursor = indptr + NN + 1;
    int* ssrc   = cursor + NN;

    // CSR build
    hipMemsetAsync(counts, 0, NN * sizeof(int), stream);
    hist_kernel<<<(EE + 255) / 256, 256, 0, stream>>>(edges, counts, EE);
    scan_block<<<(NN + 1023) / 1024, 1024, 0, stream>>>(counts, excl, bsums, NN);
    scan_tops<<<1, 64, 0, stream>>>(bsums, (NN + 1023) / 1024);
    scan_fix<<<(NN + 255) / 256, 256, 0, stream>>>(excl, bsums, indptr, cursor, NN);
    scatter_kernel<<<(EE + 255) / 256, 256, 0, stream>>>(edges, cursor, ssrc, EE);

    // weight prep
    transpose_bf16<<<dim3(8, 8, 1), 256, 0, stream>>>(head_W, headT, 256, 256, 0, 0);
    transpose_bf16<<<dim3(8, 8, 4), 256, 0, stream>>>(Wl, WzT, 256, 256, 65536, 131072);
    transpose_bf16<<<dim3(8, 8, 4), 256, 0, stream>>>(Wr, WzT + 65536, 256, 256, 65536, 131072);
    transpose_bf16<<<dim3(32, 8, 4), 256, 0, stream>>>(dense_W, denseT, 256, 1024, 262144, 262144);
    transpose_bf16<<<dim3(2, 8, 1), 256, 0, stream>>>(tail_W, tailT, 256, 64, 0, 0);
    // bf16(x) -> hnb (dead region at this point)
    convert_bf16<<<(int)(NH / 4 + 255) / 256, 256, 0, stream>>>(x, hnb, (int)(NH / 4));

    const int GX = (NN + 127) / 128;  // 157
    // head: xr = x @ head_W + head_b (fp32)
    gemm128<0><<<dim3(GX, 2), 256, 0, stream>>>(hnb, headT, head_b, xr, NN, 256);

    for (int l = 0; l < 4; ++l) {
        if (l == 0)
            ln_kernel<<<NN / 4, 256, 0, stream>>>(xr, ng_g, ng_b, hn, hnb, NN);
        else
            ln_dense<<<NN / 4, 256, 0, stream>>>(d_buf, xr, ng_g + l * 256, ng_b + l * 256, hn, hnb, NN);
        // [zl|zr] = hn @ [Wl|Wr]
        gemm128<1><<<dim3(GX, 4), 256, 0, stream>>>(hnb, WzT + (size_t)l * 131072, nullptr, zb, NN, 512);
        // fused scores + online-softmax agg + residual + LayerNorm
        gat_fused<<<(NN + 3) / 4, 256, 0, stream>>>(zb, att + l * 256, ssrc, indptr, hn,
                                                    nd_g + l * 256, nd_b + l * 256, xr, xrb, NN);
        // d = gelu(xr @ dense_W + dense_b)  (partial chunks, bf16) — clobbers zb (dead)
        gemm128<2><<<dim3(GX, 8), 256, 0, stream>>>(xrb, denseT + (size_t)l * 262144,
                                                    dense_b + l * 1024, d_buf, NN, 1024);
    }
    // hb = bf16(sum_c d + xr) -> hnb (dead); out = hb @ tail_W + tail_b
    combine_final<<<NN / 4, 256, 0, stream>>>(d_buf, xr, hnb, NN);
    gemm128<0><<<dim3(GX, 1), 256, 0, stream>>>(hnb, tailT, tail_b, out, NN, 64);
}

// Round 7
// 701.626 us; speedup vs baseline: 2.9936x; 1.0638x over previous
//
#include <hip/hip_runtime.h>
#include <cstdint>

#define NN 20000
#define EE 320000
#define DHID 256

typedef short bf16x8 __attribute__((ext_vector_type(8)));
typedef float f32x4 __attribute__((ext_vector_type(4)));

// ---------------------------------------------------------------- utilities

__device__ __forceinline__ float b2f(unsigned short u) {
    union { unsigned int i; float f; } v;
    v.i = ((unsigned int)u) << 16;
    return v.f;
}

// one uint = two packed bf16 -> two floats (2 insts)
__device__ __forceinline__ void b2f2(unsigned int w, float& lo, float& hi) {
    union { unsigned int i; float f; } a, c;
    a.i = w << 16;
    c.i = w & 0xffff0000u;
    lo = a.f;
    hi = c.f;
}

__device__ __forceinline__ unsigned short f2b(float x) {
    union { float f; unsigned int i; } v;
    v.f = x;
    unsigned int r = (v.i + 0x7FFFu + ((v.i >> 16) & 1u)) >> 16;
    return (unsigned short)r;
}

__device__ __forceinline__ float wave_sum(float v) {
#pragma unroll
    for (int m = 1; m < 64; m <<= 1) v += __shfl_xor(v, m);
    return v;
}

__device__ __forceinline__ float quad16_sum(float v) {
#pragma unroll
    for (int m = 1; m < 16; m <<= 1) v += __shfl_xor(v, m);
    return v;
}

__device__ __forceinline__ float gelu_f(float x) {
    float z = 0.7978845608028654f * (x + 0.044715f * x * x * x);
    float e = __expf(2.0f * z);
    float t = 1.0f - 2.0f / (e + 1.0f);   // tanh(z)
    return 0.5f * x * (1.0f + t);
}

// async global->LDS, 16B per lane; lds dest is wave-uniform base (+HW lane*16)
__device__ __forceinline__ void gld16(const unsigned short* g, unsigned short* lds) {
    __builtin_amdgcn_global_load_lds((const __attribute__((address_space(1))) unsigned int*)g,
                                     (__attribute__((address_space(3))) unsigned int*)lds, 16, 0, 0);
}

// ---------------------------------------------------------------- CSR build

__global__ void hist_kernel(const int* __restrict__ edges, int* __restrict__ counts, int E_) {
    int e = blockIdx.x * 256 + threadIdx.x;
    if (e >= E_) return;
    atomicAdd(&counts[edges[e * 2]], 1);
}

__global__ __launch_bounds__(1024) void scan_block(const int* __restrict__ counts,
                                                   int* __restrict__ excl,
                                                   int* __restrict__ bsums, int n) {
    __shared__ int sd[1024];
    int tid = threadIdx.x;
    int i = blockIdx.x * 1024 + tid;
    int c = (i < n) ? counts[i] : 0;
    sd[tid] = c;
    __syncthreads();
#pragma unroll
    for (int off = 1; off < 1024; off <<= 1) {
        int v = (tid >= off) ? sd[tid - off] : 0;
        __syncthreads();
        sd[tid] += v;
        __syncthreads();
    }
    if (i < n) excl[i] = sd[tid] - c;
    if (tid == 1023) bsums[blockIdx.x] = sd[1023];
}

__global__ void scan_tops(int* __restrict__ bsums, int nb) {
    if (threadIdx.x == 0 && blockIdx.x == 0) {
        int run = 0;
        for (int i = 0; i < nb; ++i) { int t = bsums[i]; bsums[i] = run; run += t; }
    }
}

__global__ void scan_fix(const int* __restrict__ excl, const int* __restrict__ bsums,
                         int* __restrict__ indptr, int* __restrict__ cursor, int n) {
    int i = blockIdx.x * 256 + threadIdx.x;
    if (i < n) {
        int v = excl[i] + bsums[i >> 10];
        indptr[i] = v;
        cursor[i] = v;
    }
    if (i == 0) indptr[n] = EE;
}

__global__ void scatter_kernel(const int* __restrict__ edges, int* __restrict__ cursor,
                               int* __restrict__ ssrc, int E_) {
    int e = blockIdx.x * 256 + threadIdx.x;
    if (e >= E_) return;
    int dstn = edges[e * 2];
    int src  = edges[e * 2 + 1];
    int pos = atomicAdd(&cursor[dstn], 1);
    ssrc[pos] = src;
}

// ---------------------------------------------------------------- weight transpose: W (K x M) fp32 -> Wt (M x K) bf16

__global__ __launch_bounds__(256) void transpose_bf16(const float* __restrict__ W,
                                                      unsigned short* __restrict__ Wt,
                                                      int K, int M, size_t lsW, size_t lsT) {
    W  += (size_t)blockIdx.z * lsW;
    Wt += (size_t)blockIdx.z * lsT;
    __shared__ float sm[32][33];
    int m0 = blockIdx.x * 32, k0 = blockIdx.y * 32;
    int tx = threadIdx.x & 31, ty = threadIdx.x >> 5;
#pragma unroll
    for (int i = 0; i < 4; ++i)
        sm[ty + i * 8][tx] = W[(size_t)(k0 + ty + i * 8) * M + m0 + tx];
    __syncthreads();
#pragma unroll
    for (int i = 0; i < 4; ++i)
        Wt[(size_t)(m0 + ty + i * 8) * K + k0 + tx] = f2b(sm[tx][ty + i * 8]);
}

__global__ void convert_bf16(const float* __restrict__ in, unsigned short* __restrict__ out, int n4) {
    int i = blockIdx.x * 256 + threadIdx.x;
    if (i >= n4) return;
    float4 v = *(const float4*)(in + (size_t)i * 4);
    ushort4 o;
    o.x = f2b(v.x); o.y = f2b(v.y); o.z = f2b(v.z); o.w = f2b(v.w);
    *(ushort4*)(out + (size_t)i * 4) = o;
}

// ---------------------------------------------------------------- LayerNorm (plain, fp32 in -> fp32 + bf16)

__global__ __launch_bounds__(256) void ln_kernel(const float* __restrict__ X,
                                                 const float* __restrict__ g,
                                                 const float* __restrict__ b,
                                                 float* __restrict__ Y,
                                                 unsigned short* __restrict__ Yb, int nrows) {
    int row = blockIdx.x * 4 + (threadIdx.x >> 6);
    int lane = threadIdx.x & 63;
    if (row >= nrows) return;
    float4 v = *(const float4*)(X + (size_t)row * DHID + lane * 4);
    float sum = wave_sum(v.x + v.y + v.z + v.w);
    float sq  = wave_sum(v.x * v.x + v.y * v.y + v.z * v.z + v.w * v.w);
    float mean = sum * (1.0f / DHID);
    float var  = sq * (1.0f / DHID) - mean * mean;
    float r = rsqrtf(fmaxf(var, 0.0f) + 1e-3f);
    float4 gv = *(const float4*)(g + lane * 4);
    float4 bv = *(const float4*)(b + lane * 4);
    float4 o;
    o.x = (v.x - mean) * r * gv.x + bv.x;
    o.y = (v.y - mean) * r * gv.y + bv.y;
    o.z = (v.z - mean) * r * gv.z + bv.z;
    o.w = (v.w - mean) * r * gv.w + bv.w;
    *(float4*)(Y + (size_t)row * DHID + lane * 4) = o;
    ushort4 ob;
    ob.x = f2b(o.x); ob.y = f2b(o.y); ob.z = f2b(o.z); ob.w = f2b(o.w);
    *(ushort4*)(Yb + (size_t)row * DHID + lane * 4) = ob;
}

// LayerNorm fused with dense-chunk-sum + residual: v = sum_c d[n][c*256+j] + xr[n][j]; LN(v)
__global__ __launch_bounds__(256) void ln_dense(const unsigned short* __restrict__ d,
                                                const float* __restrict__ xr,
                                                const float* __restrict__ g,
                                                const float* __restrict__ b,
                                                float* __restrict__ Y,
                                                unsigned short* __restrict__ Yb, int nrows) {
    int row = blockIdx.x * 4 + (threadIdx.x >> 6);
    int lane = threadIdx.x & 63;
    if (row >= nrows) return;
    float4 v = *(const float4*)(xr + (size_t)row * DHID + lane * 4);
#pragma unroll
    for (int c = 0; c < 4; ++c) {
        ushort4 t = *(const ushort4*)(d + (size_t)row * 1024 + c * 256 + lane * 4);
        v.x += b2f(t.x); v.y += b2f(t.y); v.z += b2f(t.z); v.w += b2f(t.w);
    }
    float sum = wave_sum(v.x + v.y + v.z + v.w);
    float sq  = wave_sum(v.x * v.x + v.y * v.y + v.z * v.z + v.w * v.w);
    float mean = sum * (1.0f / DHID);
    float var  = sq * (1.0f / DHID) - mean * mean;
    float r = rsqrtf(fmaxf(var, 0.0f) + 1e-3f);
    float4 gv = *(const float4*)(g + lane * 4);
    float4 bv = *(const float4*)(b + lane * 4);
    float4 o;
    o.x = (v.x - mean) * r * gv.x + bv.x;
    o.y = (v.y - mean) * r * gv.y + bv.y;
    o.z = (v.z - mean) * r * gv.z + bv.z;
    o.w = (v.w - mean) * r * gv.w + bv.w;
    *(float4*)(Y + (size_t)row * DHID + lane * 4) = o;
    ushort4 ob;
    ob.x = f2b(o.x); ob.y = f2b(o.y); ob.z = f2b(o.z); ob.w = f2b(o.w);
    *(ushort4*)(Yb + (size_t)row * DHID + lane * 4) = ob;
}

// final combine (no LN): hb = bf16(sum_c d + xr)
__global__ __launch_bounds__(256) void combine_final(const unsigned short* __restrict__ d,
                                                     const float* __restrict__ xr,
                                                     unsigned short* __restrict__ hb, int nrows) {
    int row = blockIdx.x * 4 + (threadIdx.x >> 6);
    int lane = threadIdx.x & 63;
    if (row >= nrows) return;
    float4 v = *(const float4*)(xr + (size_t)row * DHID + lane * 4);
#pragma unroll
    for (int c = 0; c < 4; ++c) {
        ushort4 t = *(const ushort4*)(d + (size_t)row * 1024 + c * 256 + lane * 4);
        v.x += b2f(t.x); v.y += b2f(t.y); v.z += b2f(t.z); v.w += b2f(t.w);
    }
    ushort4 ob;
    ob.x = f2b(v.x); ob.y = f2b(v.y); ob.z = f2b(v.z); ob.w = f2b(v.w);
    *(ushort4*)(hb + (size_t)row * DHID + lane * 4) = ob;
}

// ---------------------------------------------------------------- MFMA GEMM, 128x128 tile, LDS-staged (m97 style)
// A: nrows x 256 bf16 (k contig); B: ncols x 256 bf16 (k contig, i.e. W^T)
// EP: 0 = fp32 out (+bias), 1 = bf16 out, 2 = bf16 gelu(acc + bias)

template <int EP>
__global__ __launch_bounds__(256, 3) void gemm128(const unsigned short* __restrict__ A,
                                                  const unsigned short* __restrict__ B,
                                                  const float* __restrict__ bias,
                                                  void* __restrict__ Cv, int nrows, int ncols) {
    // LDS layout: rowgroup (16 rows) blocks of 512 shorts:
    //   offset(row,g) = (row>>4)*512 + g*128 + (row&15)*8   (g = k-group of 8 bf16)
    __shared__ unsigned short As[128 * 32];
    __shared__ unsigned short Bs[128 * 32];
    const int tid  = threadIdx.x;
    const int w    = tid >> 6, lane = tid & 63;
    const int quad = lane >> 4, l16 = lane & 15;
    const int wm = w >> 1, wn = w & 1;
    const int bm = blockIdx.x * 128, bn = blockIdx.y * 128;

    const int srow = lane & 15;
    const int sg   = lane >> 4;
    int ga0 = min(bm + w * 32 + srow,      nrows - 1);
    int ga1 = min(bm + w * 32 + 16 + srow, nrows - 1);
    int gb0 = min(bn + w * 32 + srow,      ncols - 1);
    int gb1 = min(bn + w * 32 + 16 + srow, ncols - 1);
    const unsigned short* Ap0 = A + (size_t)ga0 * 256 + sg * 8;
    const unsigned short* Ap1 = A + (size_t)ga1 * 256 + sg * 8;
    const unsigned short* Bp0 = B + (size_t)gb0 * 256 + sg * 8;
    const unsigned short* Bp1 = B + (size_t)gb1 * 256 + sg * 8;
    unsigned short* la0 = As + (2 * w) * 512;
    unsigned short* la1 = As + (2 * w + 1) * 512;
    unsigned short* lb0 = Bs + (2 * w) * 512;
    unsigned short* lb1 = Bs + (2 * w + 1) * 512;

    f32x4 acc[4][4] = {};
    for (int k0 = 0; k0 < 256; k0 += 32) {
        gld16(Ap0 + k0, la0);
        gld16(Ap1 + k0, la1);
        gld16(Bp0 + k0, lb0);
        gld16(Bp1 + k0, lb1);
        __syncthreads();
        bf16x8 a[4], b[4];
#pragma unroll
        for (int mi = 0; mi < 4; ++mi)
            a[mi] = *(const bf16x8*)(As + (wm * 4 + mi) * 512 + quad * 128 + l16 * 8);
#pragma unroll
        for (int ni = 0; ni < 4; ++ni)
            b[ni] = *(const bf16x8*)(Bs + (wn * 4 + ni) * 512 + quad * 128 + l16 * 8);
#pragma unroll
        for (int mi = 0; mi < 4; ++mi)
#pragma unroll
            for (int ni = 0; ni < 4; ++ni)
                acc[mi][ni] = __builtin_amdgcn_mfma_f32_16x16x32_bf16(a[mi], b[ni], acc[mi][ni], 0, 0, 0);
        __syncthreads();
    }

#pragma unroll
    for (int ni = 0; ni < 4; ++ni) {
        int col = bn + wn * 64 + ni * 16 + l16;
        if (col >= ncols) continue;
        float bv = (EP != 1 && bias) ? bias[col] : 0.0f;
#pragma unroll
        for (int mi = 0; mi < 4; ++mi) {
#pragma unroll
            for (int r = 0; r < 4; ++r) {
                int row = bm + wm * 64 + mi * 16 + quad * 4 + r;
                if (row >= nrows) continue;
                float v = acc[mi][ni][r] + bv;
                if (EP == 0) ((float*)Cv)[(size_t)row * ncols + col] = v;
                else if (EP == 1) ((unsigned short*)Cv)[(size_t)row * ncols + col] = f2b(v);
                else ((unsigned short*)Cv)[(size_t)row * ncols + col] = f2b(gelu_f(v));
            }
        }
    }
}

// ---------------------------------------------------------------- fused GAT edge phase: online-softmax scores+agg+residual+LN
// zb stacked rows [n][512] = [zl | zr]. One wave per node; head h = quad
// (lanes 16h..16h+15 hold features h*64..h*64+63, 4 per lane).
// Pair-unrolled: 2 gathers in flight, joint softmax update (1 corr per pair).

__global__ __launch_bounds__(256) void gat_fused(const unsigned short* __restrict__ zb,
                                                 const float* __restrict__ att,
                                                 const int* __restrict__ ssrc,
                                                 const int* __restrict__ indptr,
                                                 const float* __restrict__ hn,
                                                 const float* __restrict__ g,
                                                 const float* __restrict__ b,
                                                 float* __restrict__ xr,
                                                 unsigned short* __restrict__ xrb, int nrows) {
    int wid = threadIdx.x >> 6;
    int lane = threadIdx.x & 63;
    int n = blockIdx.x * 4 + wid;
    if (n >= nrows) return;
    int start = indptr[n];
    int end = indptr[n + 1];

    ushort4 zlu = *(const ushort4*)(zb + (size_t)n * 512 + lane * 4);
    float zl0 = b2f(zlu.x), zl1 = b2f(zlu.y), zl2 = b2f(zlu.z), zl3 = b2f(zlu.w);
    float4 a4 = *(const float4*)(att + lane * 4);
    size_t idx = (size_t)n * DHID + lane * 4;
    float4 rres = *(const float4*)(hn + idx);

    float m = -3.0e38f, denom = 0.f;
    float ax = 0.f, ay = 0.f, az = 0.f, aw = 0.f;

    const uint2* zrp = (const uint2*)(zb + 256);  // row n: zrp[n*128 + lane]
    uint2 c0 = make_uint2(0, 0), c1 = make_uint2(0, 0);
    if (start < end) {
        int i0 = ssrc[start];
        int i1 = ssrc[(start + 1 < end) ? start + 1 : start];
        c0 = zrp[(size_t)i0 * 128 + lane];
        c1 = zrp[(size_t)i1 * 128 + lane];
    }
    for (int p = start; p < end; p += 2) {
        uint2 u0 = c0, u1 = c1;
        bool val1 = (p + 1 < end);
        if (p + 2 < end) {
            int j0 = ssrc[p + 2];
            int j1 = ssrc[(p + 3 < end) ? p + 3 : p + 2];
            c0 = zrp[(size_t)j0 * 128 + lane];
            c1 = zrp[(size_t)j1 * 128 + lane];
        }
        float z00, z01, z02, z03, z10, z11, z12, z13;
        b2f2(u0.x, z00, z01); b2f2(u0.y, z02, z03);
        b2f2(u1.x, z10, z11); b2f2(u1.y, z12, z13);

        float v0 = zl0 + z00, v1 = zl1 + z01, v2 = zl2 + z02, v3 = zl3 + z03;
        float t0 = zl0 + z10, t1 = zl1 + z11, t2 = zl2 + z12, t3 = zl3 + z13;
        v0 = (v0 > 0.f) ? v0 : 0.2f * v0;
        v1 = (v1 > 0.f) ? v1 : 0.2f * v1;
        v2 = (v2 > 0.f) ? v2 : 0.2f * v2;
        v3 = (v3 > 0.f) ? v3 : 0.2f * v3;
        t0 = (t0 > 0.f) ? t0 : 0.2f * t0;
        t1 = (t1 > 0.f) ? t1 : 0.2f * t1;
        t2 = (t2 > 0.f) ? t2 : 0.2f * t2;
        t3 = (t3 > 0.f) ? t3 : 0.2f * t3;
        float part0 = a4.x * v0 + a4.y * v1 + a4.z * v2 + a4.w * v3;
        float part1 = a4.x * t0 + a4.y * t1 + a4.z * t2 + a4.w * t3;
        float sp0 = quad16_sum(part0);      // per-head (quad) score
        float sp1 = quad16_sum(part1);
        if (!val1) sp1 = -3.0e38f;          // sentinel: weight underflows to 0
        float newm = fmaxf(m, fmaxf(sp0, sp1));
        float corr = __expf(m - newm);      // 0 on first pair
        float w0 = __expf(sp0 - newm);
        float w1 = __expf(sp1 - newm);
        denom = denom * corr + w0 + w1;
        ax = ax * corr + w0 * z00 + w1 * z10;
        ay = ay * corr + w0 * z01 + w1 * z11;
        az = az * corr + w0 * z02 + w1 * z12;
        aw = aw * corr + w0 * z03 + w1 * z13;
        m = newm;
    }
    float inv = 1.0f / (denom + 1e-9f);
    float4 o;
    o.x = ax * inv + rres.x;
    o.y = ay * inv + rres.y;
    o.z = az * inv + rres.z;
    o.w = aw * inv + rres.w;
    // fused LayerNorm (full 64-lane row reduction)
    float sum = wave_sum(o.x + o.y + o.z + o.w);
    float sq  = wave_sum(o.x * o.x + o.y * o.y + o.z * o.z + o.w * o.w);
    float mean = sum * (1.0f / DHID);
    float var  = sq * (1.0f / DHID) - mean * mean;
    float rr = rsqrtf(fmaxf(var, 0.0f) + 1e-3f);
    float4 gv = *(const float4*)(g + lane * 4);
    float4 bv = *(const float4*)(b + lane * 4);
    float4 y;
    y.x = (o.x - mean) * rr * gv.x + bv.x;
    y.y = (o.y - mean) * rr * gv.y + bv.y;
    y.z = (o.z - mean) * rr * gv.z + bv.z;
    y.w = (o.w - mean) * rr * gv.w + bv.w;
    *(float4*)(xr + idx) = y;
    ushort4 ob;
    ob.x = f2b(y.x); ob.y = f2b(y.y); ob.z = f2b(y.z); ob.w = f2b(y.w);
    *(ushort4*)(xrb + idx) = ob;
}

// ---------------------------------------------------------------- host

extern "C" void kernel_launch(void* const* d_in, const int* in_sizes, int n_in,
                              void* d_out, int out_size, void* d_ws, size_t ws_size,
                              hipStream_t stream) {
    const float* x       = (const float*)d_in[0];
    const float* head_W  = (const float*)d_in[1];
    const float* head_b  = (const float*)d_in[2];
    const float* ng_g    = (const float*)d_in[3];
    const float* ng_b    = (const float*)d_in[4];
    const float* Wl      = (const float*)d_in[5];
    const float* Wr      = (const float*)d_in[6];
    const float* att     = (const float*)d_in[7];
    const float* nd_g    = (const float*)d_in[8];
    const float* nd_b    = (const float*)d_in[9];
    const float* dense_W = (const float*)d_in[10];
    const float* dense_b = (const float*)d_in[11];
    const float* tail_W  = (const float*)d_in[12];
    const float* tail_b  = (const float*)d_in[13];
    const int*   edges   = (const int*)d_in[14];
    float* out = (float*)d_out;

    const size_t NH = (size_t)NN * DHID;  // 5,120,000
    // ---- workspace layout (liveness-checked; zb/d union is deliberate) ----
    float* xr = (float*)d_ws;                           // NH f32  (head-out, then agg out)
    float* hn = xr + NH;                                // NH f32  (LN out, GAT residual)
    unsigned short* hnb = (unsigned short*)(hn + NH);   // NH bf16 (x-bf16 / LN-out bf16 / final hb)
    unsigned short* xrb = hnb + NH;                     // NH bf16
    unsigned short* U   = xrb + NH;                     // union region, 4*NH shorts (40.96 MB)
    unsigned short* zb  = U;                            //   N x 512 bf16   (dies at gat_fused)
    unsigned short* d_buf = U;                          //   N x 1024 bf16  (written after gat_fused, dies at ln_dense)
    unsigned short* headT  = U + 4 * NH;
    unsigned short* WzT    = headT + 65536;             // 4 x (512 x 256)
    unsigned short* denseT = WzT + 524288;              // 4 x (1024 x 256)
    unsigned short* tailT  = denseT + 1048576;          // 64 x 256
    int* counts = (int*)(tailT + 16384);
    int* bsums  = counts + NN;
    int* excl   = bsums + 32;
    int* indptr = excl + NN;
    int* cursor = indptr + NN + 1;
    int* ssrc   = cursor + NN;

    // CSR build
    hipMemsetAsync(counts, 0, NN * sizeof(int), stream);
    hist_kernel<<<(EE + 255) / 256, 256, 0, stream>>>(edges, counts, EE);
    scan_block<<<(NN + 1023) / 1024, 1024, 0, stream>>>(counts, excl, bsums, NN);
    scan_tops<<<1, 64, 0, stream>>>(bsums, (NN + 1023) / 1024);
    scan_fix<<<(NN + 255) / 256, 256, 0, stream>>>(excl, bsums, indptr, cursor, NN);
    scatter_kernel<<<(EE + 255) / 256, 256, 0, stream>>>(edges, cursor, ssrc, EE);

    // weight prep
    transpose_bf16<<<dim3(8, 8, 1), 256, 0, stream>>>(head_W, headT, 256, 256, 0, 0);
    transpose_bf16<<<dim3(8, 8, 4), 256, 0, stream>>>(Wl, WzT, 256, 256, 65536, 131072);
    transpose_bf16<<<dim3(8, 8, 4), 256, 0, stream>>>(Wr, WzT + 65536, 256, 256, 65536, 131072);
    transpose_bf16<<<dim3(32, 8, 4), 256, 0, stream>>>(dense_W, denseT, 256, 1024, 262144, 262144);
    transpose_bf16<<<dim3(2, 8, 1), 256, 0, stream>>>(tail_W, tailT, 256, 64, 0, 0);
    // bf16(x) -> hnb (dead region at this point)
    convert_bf16<<<(int)(NH / 4 + 255) / 256, 256, 0, stream>>>(x, hnb, (int)(NH / 4));

    const int GX = (NN + 127) / 128;  // 157
    // head: xr = x @ head_W + head_b (fp32)
    gemm128<0><<<dim3(GX, 2), 256, 0, stream>>>(hnb, headT, head_b, xr, NN, 256);

    for (int l = 0; l < 4; ++l) {
        if (l == 0)
            ln_kernel<<<NN / 4, 256, 0, stream>>>(xr, ng_g, ng_b, hn, hnb, NN);
        else
            ln_dense<<<NN / 4, 256, 0, stream>>>(d_buf, xr, ng_g + l * 256, ng_b + l * 256, hn, hnb, NN);
        // [zl|zr] = hn @ [Wl|Wr]
        gemm128<1><<<dim3(GX, 4), 256, 0, stream>>>(hnb, WzT + (size_t)l * 131072, nullptr, zb, NN, 512);
        // fused scores + online-softmax agg + residual + LayerNorm
        gat_fused<<<(NN + 3) / 4, 256, 0, stream>>>(zb, att + l * 256, ssrc, indptr, hn,
                                                    nd_g + l * 256, nd_b + l * 256, xr, xrb, NN);
        // d = gelu(xr @ dense_W + dense_b)  (partial chunks, bf16) — clobbers zb (dead)
        gemm128<2><<<dim3(GX, 8), 256, 0, stream>>>(xrb, denseT + (size_t)l * 262144,
                                                    dense_b + l * 1024, d_buf, NN, 1024);
    }
    // hb = bf16(sum_c d + xr) -> hnb (dead); out = hb @ tail_W + tail_b
    combine_final<<<NN / 4, 256, 0, stream>>>(d_buf, xr, hnb, NN);
    gemm128<0><<<dim3(GX, 1), 256, 0, stream>>>(hnb, tailT, tail_b, out, NN, 64);
}

// Round 8
// 644.842 us; speedup vs baseline: 3.2572x; 1.0881x over previous
//
#include <hip/hip_runtime.h>
#include <cstdint>

#define NN 20000
#define EE 320000
#define DHID 256

typedef short bf16x8 __attribute__((ext_vector_type(8)));
typedef float f32x4 __attribute__((ext_vector_type(4)));

// ---------------------------------------------------------------- utilities

__device__ __forceinline__ float b2f(unsigned short u) {
    union { unsigned int i; float f; } v;
    v.i = ((unsigned int)u) << 16;
    return v.f;
}

// one uint = two packed bf16 -> two floats
__device__ __forceinline__ void b2f2(unsigned int w, float& lo, float& hi) {
    union { unsigned int i; float f; } a, c;
    a.i = w << 16;
    c.i = w & 0xffff0000u;
    lo = a.f;
    hi = c.f;
}

__device__ __forceinline__ unsigned short f2b(float x) {
    union { float f; unsigned int i; } v;
    v.f = x;
    unsigned int r = (v.i + 0x7FFFu + ((v.i >> 16) & 1u)) >> 16;
    return (unsigned short)r;
}

__device__ __forceinline__ float wave_sum(float v) {
#pragma unroll
    for (int m = 1; m < 64; m <<= 1) v += __shfl_xor(v, m);
    return v;
}

__device__ __forceinline__ float quad16_sum(float v) {
#pragma unroll
    for (int m = 1; m < 16; m <<= 1) v += __shfl_xor(v, m);
    return v;
}

__device__ __forceinline__ float gelu_f(float x) {
    float z = 0.7978845608028654f * (x + 0.044715f * x * x * x);
    float e = __expf(2.0f * z);
    float t = 1.0f - 2.0f / (e + 1.0f);   // tanh(z)
    return 0.5f * x * (1.0f + t);
}

// async global->LDS, 16B per lane; lds dest is wave-uniform base (+HW lane*16)
__device__ __forceinline__ void gld16(const unsigned short* g, unsigned short* lds) {
    __builtin_amdgcn_global_load_lds((const __attribute__((address_space(1))) unsigned int*)g,
                                     (__attribute__((address_space(3))) unsigned int*)lds, 16, 0, 0);
}

// ---------------------------------------------------------------- CSR build

__global__ void hist_kernel(const int* __restrict__ edges, int* __restrict__ counts, int E_) {
    int e = blockIdx.x * 256 + threadIdx.x;
    if (e >= E_) return;
    atomicAdd(&counts[edges[e * 2]], 1);
}

__global__ __launch_bounds__(1024) void scan_block(const int* __restrict__ counts,
                                                   int* __restrict__ excl,
                                                   int* __restrict__ bsums, int n) {
    __shared__ int sd[1024];
    int tid = threadIdx.x;
    int i = blockIdx.x * 1024 + tid;
    int c = (i < n) ? counts[i] : 0;
    sd[tid] = c;
    __syncthreads();
#pragma unroll
    for (int off = 1; off < 1024; off <<= 1) {
        int v = (tid >= off) ? sd[tid - off] : 0;
        __syncthreads();
        sd[tid] += v;
        __syncthreads();
    }
    if (i < n) excl[i] = sd[tid] - c;
    if (tid == 1023) bsums[blockIdx.x] = sd[1023];
}

__global__ void scan_tops(int* __restrict__ bsums, int nb) {
    if (threadIdx.x == 0 && blockIdx.x == 0) {
        int run = 0;
        for (int i = 0; i < nb; ++i) { int t = bsums[i]; bsums[i] = run; run += t; }
    }
}

__global__ void scan_fix(const int* __restrict__ excl, const int* __restrict__ bsums,
                         int* __restrict__ indptr, int* __restrict__ cursor, int n) {
    int i = blockIdx.x * 256 + threadIdx.x;
    if (i < n) {
        int v = excl[i] + bsums[i >> 10];
        indptr[i] = v;
        cursor[i] = v;
    }
    if (i == 0) indptr[n] = EE;
}

__global__ void scatter_kernel(const int* __restrict__ edges, int* __restrict__ cursor,
                               int* __restrict__ ssrc, int E_) {
    int e = blockIdx.x * 256 + threadIdx.x;
    if (e >= E_) return;
    int dstn = edges[e * 2];
    int src  = edges[e * 2 + 1];
    int pos = atomicAdd(&cursor[dstn], 1);
    ssrc[pos] = src;
}

// ---------------------------------------------------------------- weight transpose: W (K x M) fp32 -> Wt (M x K) bf16

__global__ __launch_bounds__(256) void transpose_bf16(const float* __restrict__ W,
                                                      unsigned short* __restrict__ Wt,
                                                      int K, int M, size_t lsW, size_t lsT) {
    W  += (size_t)blockIdx.z * lsW;
    Wt += (size_t)blockIdx.z * lsT;
    __shared__ float sm[32][33];
    int m0 = blockIdx.x * 32, k0 = blockIdx.y * 32;
    int tx = threadIdx.x & 31, ty = threadIdx.x >> 5;
#pragma unroll
    for (int i = 0; i < 4; ++i)
        sm[ty + i * 8][tx] = W[(size_t)(k0 + ty + i * 8) * M + m0 + tx];
    __syncthreads();
#pragma unroll
    for (int i = 0; i < 4; ++i)
        Wt[(size_t)(m0 + ty + i * 8) * K + k0 + tx] = f2b(sm[tx][ty + i * 8]);
}

__global__ void convert_bf16(const float* __restrict__ in, unsigned short* __restrict__ out, int n4) {
    int i = blockIdx.x * 256 + threadIdx.x;
    if (i >= n4) return;
    float4 v = *(const float4*)(in + (size_t)i * 4);
    ushort4 o;
    o.x = f2b(v.x); o.y = f2b(v.y); o.z = f2b(v.z); o.w = f2b(v.w);
    *(ushort4*)(out + (size_t)i * 4) = o;
}

// ---------------------------------------------------------------- LayerNorm (plain, fp32 in -> fp32 + bf16)

__global__ __launch_bounds__(256) void ln_kernel(const float* __restrict__ X,
                                                 const float* __restrict__ g,
                                                 const float* __restrict__ b,
                                                 float* __restrict__ Y,
                                                 unsigned short* __restrict__ Yb, int nrows) {
    int row = blockIdx.x * 4 + (threadIdx.x >> 6);
    int lane = threadIdx.x & 63;
    if (row >= nrows) return;
    float4 v = *(const float4*)(X + (size_t)row * DHID + lane * 4);
    float sum = wave_sum(v.x + v.y + v.z + v.w);
    float sq  = wave_sum(v.x * v.x + v.y * v.y + v.z * v.z + v.w * v.w);
    float mean = sum * (1.0f / DHID);
    float var  = sq * (1.0f / DHID) - mean * mean;
    float r = rsqrtf(fmaxf(var, 0.0f) + 1e-3f);
    float4 gv = *(const float4*)(g + lane * 4);
    float4 bv = *(const float4*)(b + lane * 4);
    float4 o;
    o.x = (v.x - mean) * r * gv.x + bv.x;
    o.y = (v.y - mean) * r * gv.y + bv.y;
    o.z = (v.z - mean) * r * gv.z + bv.z;
    o.w = (v.w - mean) * r * gv.w + bv.w;
    *(float4*)(Y + (size_t)row * DHID + lane * 4) = o;
    ushort4 ob;
    ob.x = f2b(o.x); ob.y = f2b(o.y); ob.z = f2b(o.z); ob.w = f2b(o.w);
    *(ushort4*)(Yb + (size_t)row * DHID + lane * 4) = ob;
}

// LayerNorm fused with dense-chunk-sum + residual
__global__ __launch_bounds__(256) void ln_dense(const unsigned short* __restrict__ d,
                                                const float* __restrict__ xr,
                                                const float* __restrict__ g,
                                                const float* __restrict__ b,
                                                float* __restrict__ Y,
                                                unsigned short* __restrict__ Yb, int nrows) {
    int row = blockIdx.x * 4 + (threadIdx.x >> 6);
    int lane = threadIdx.x & 63;
    if (row >= nrows) return;
    float4 v = *(const float4*)(xr + (size_t)row * DHID + lane * 4);
#pragma unroll
    for (int c = 0; c < 4; ++c) {
        ushort4 t = *(const ushort4*)(d + (size_t)row * 1024 + c * 256 + lane * 4);
        v.x += b2f(t.x); v.y += b2f(t.y); v.z += b2f(t.z); v.w += b2f(t.w);
    }
    float sum = wave_sum(v.x + v.y + v.z + v.w);
    float sq  = wave_sum(v.x * v.x + v.y * v.y + v.z * v.z + v.w * v.w);
    float mean = sum * (1.0f / DHID);
    float var  = sq * (1.0f / DHID) - mean * mean;
    float r = rsqrtf(fmaxf(var, 0.0f) + 1e-3f);
    float4 gv = *(const float4*)(g + lane * 4);
    float4 bv = *(const float4*)(b + lane * 4);
    float4 o;
    o.x = (v.x - mean) * r * gv.x + bv.x;
    o.y = (v.y - mean) * r * gv.y + bv.y;
    o.z = (v.z - mean) * r * gv.z + bv.z;
    o.w = (v.w - mean) * r * gv.w + bv.w;
    *(float4*)(Y + (size_t)row * DHID + lane * 4) = o;
    ushort4 ob;
    ob.x = f2b(o.x); ob.y = f2b(o.y); ob.z = f2b(o.z); ob.w = f2b(o.w);
    *(ushort4*)(Yb + (size_t)row * DHID + lane * 4) = ob;
}

// final combine (no LN): hb = bf16(sum_c d + xr)
__global__ __launch_bounds__(256) void combine_final(const unsigned short* __restrict__ d,
                                                     const float* __restrict__ xr,
                                                     unsigned short* __restrict__ hb, int nrows) {
    int row = blockIdx.x * 4 + (threadIdx.x >> 6);
    int lane = threadIdx.x & 63;
    if (row >= nrows) return;
    float4 v = *(const float4*)(xr + (size_t)row * DHID + lane * 4);
#pragma unroll
    for (int c = 0; c < 4; ++c) {
        ushort4 t = *(const ushort4*)(d + (size_t)row * 1024 + c * 256 + lane * 4);
        v.x += b2f(t.x); v.y += b2f(t.y); v.z += b2f(t.z); v.w += b2f(t.w);
    }
    ushort4 ob;
    ob.x = f2b(v.x); ob.y = f2b(v.y); ob.z = f2b(v.z); ob.w = f2b(v.w);
    *(ushort4*)(hb + (size_t)row * DHID + lane * 4) = ob;
}

// ---------------------------------------------------------------- MFMA GEMM, 128x128 tile, LDS-staged
// A: nrows x 256 bf16 (k contig); B: ncols x 256 bf16 (k contig, i.e. W^T)
// EP: 0 = fp32 out (+bias), 1 = bf16 out, 2 = bf16 gelu(acc + bias)
// Grid x padded to multiple of 8 (empty blocks return) so XCD = bx & 7 for all by:
// all column passes of a row-block hit the same XCD's L2 -> A fetched once.
// bf16 epilogue staged through padded LDS tile -> fully coalesced 16B stores.

#define CS_STRIDE 140  // 128 + 12 shorts: quad rows (4 apart) land on distinct banks

template <int EP>
__global__ __launch_bounds__(256, 3) void gemm128(const unsigned short* __restrict__ A,
                                                  const unsigned short* __restrict__ B,
                                                  const float* __restrict__ bias,
                                                  void* __restrict__ Cv, int nrows, int ncols) {
    __shared__ unsigned short As[128 * 32];
    __shared__ unsigned short Bs[128 * 32];
    __shared__ unsigned short Cs[128 * CS_STRIDE];
    const int bm = blockIdx.x * 128, bn = blockIdx.y * 128;
    if (bm >= nrows) return;  // grid-x padding
    const int tid  = threadIdx.x;
    const int w    = tid >> 6, lane = tid & 63;
    const int quad = lane >> 4, l16 = lane & 15;
    const int wm = w >> 1, wn = w & 1;

    const int srow = lane & 15;
    const int sg   = lane >> 4;
    int ga0 = min(bm + w * 32 + srow,      nrows - 1);
    int ga1 = min(bm + w * 32 + 16 + srow, nrows - 1);
    int gb0 = min(bn + w * 32 + srow,      ncols - 1);
    int gb1 = min(bn + w * 32 + 16 + srow, ncols - 1);
    const unsigned short* Ap0 = A + (size_t)ga0 * 256 + sg * 8;
    const unsigned short* Ap1 = A + (size_t)ga1 * 256 + sg * 8;
    const unsigned short* Bp0 = B + (size_t)gb0 * 256 + sg * 8;
    const unsigned short* Bp1 = B + (size_t)gb1 * 256 + sg * 8;
    unsigned short* la0 = As + (2 * w) * 512;
    unsigned short* la1 = As + (2 * w + 1) * 512;
    unsigned short* lb0 = Bs + (2 * w) * 512;
    unsigned short* lb1 = Bs + (2 * w + 1) * 512;

    f32x4 acc[4][4] = {};
    for (int k0 = 0; k0 < 256; k0 += 32) {
        gld16(Ap0 + k0, la0);
        gld16(Ap1 + k0, la1);
        gld16(Bp0 + k0, lb0);
        gld16(Bp1 + k0, lb1);
        __syncthreads();
        bf16x8 a[4], b[4];
#pragma unroll
        for (int mi = 0; mi < 4; ++mi)
            a[mi] = *(const bf16x8*)(As + (wm * 4 + mi) * 512 + quad * 128 + l16 * 8);
#pragma unroll
        for (int ni = 0; ni < 4; ++ni)
            b[ni] = *(const bf16x8*)(Bs + (wn * 4 + ni) * 512 + quad * 128 + l16 * 8);
#pragma unroll
        for (int mi = 0; mi < 4; ++mi)
#pragma unroll
            for (int ni = 0; ni < 4; ++ni)
                acc[mi][ni] = __builtin_amdgcn_mfma_f32_16x16x32_bf16(a[mi], b[ni], acc[mi][ni], 0, 0, 0);
        __syncthreads();
    }

    if (EP == 0) {
        // fp32 out (head/tail): direct stores
#pragma unroll
        for (int ni = 0; ni < 4; ++ni) {
            int col = bn + wn * 64 + ni * 16 + l16;
            if (col >= ncols) continue;
            float bv = bias ? bias[col] : 0.0f;
#pragma unroll
            for (int mi = 0; mi < 4; ++mi) {
#pragma unroll
                for (int r = 0; r < 4; ++r) {
                    int row = bm + wm * 64 + mi * 16 + quad * 4 + r;
                    if (row < nrows) ((float*)Cv)[(size_t)row * ncols + col] = acc[mi][ni][r] + bv;
                }
            }
        }
    } else {
        // bf16 out: stage tile in LDS, then coalesced 16B stores
#pragma unroll
        for (int ni = 0; ni < 4; ++ni) {
            int lc = wn * 64 + ni * 16 + l16;
            float bv = (EP == 2) ? bias[bn + lc] : 0.0f;
#pragma unroll
            for (int mi = 0; mi < 4; ++mi) {
#pragma unroll
                for (int r = 0; r < 4; ++r) {
                    int lr = wm * 64 + mi * 16 + quad * 4 + r;
                    float v = acc[mi][ni][r] + bv;
                    Cs[lr * CS_STRIDE + lc] = f2b(EP == 2 ? gelu_f(v) : v);
                }
            }
        }
        __syncthreads();
#pragma unroll
        for (int i = 0; i < 8; ++i) {
            int id = tid + 256 * i;          // 0..2047
            int lr = id >> 4;                // 0..127
            int lc = (id & 15) * 8;          // 0..120
            int grow = bm + lr;
            if (grow < nrows) {
                uint4 val = *(const uint4*)(Cs + lr * CS_STRIDE + lc);
                *(uint4*)((unsigned short*)Cv + (size_t)grow * ncols + bn + lc) = val;
            }
        }
    }
}

// ---------------------------------------------------------------- fused GAT edge phase (online softmax, pair-unrolled)

__global__ __launch_bounds__(256) void gat_fused(const unsigned short* __restrict__ zb,
                                                 const float* __restrict__ att,
                                                 const int* __restrict__ ssrc,
                                                 const int* __restrict__ indptr,
                                                 const float* __restrict__ hn,
                                                 const float* __restrict__ g,
                                                 const float* __restrict__ b,
                                                 float* __restrict__ xr,
                                                 unsigned short* __restrict__ xrb, int nrows) {
    int wid = threadIdx.x >> 6;
    int lane = threadIdx.x & 63;
    int n = blockIdx.x * 4 + wid;
    if (n >= nrows) return;
    int start = indptr[n];
    int end = indptr[n + 1];

    ushort4 zlu = *(const ushort4*)(zb + (size_t)n * 512 + lane * 4);
    float zl0 = b2f(zlu.x), zl1 = b2f(zlu.y), zl2 = b2f(zlu.z), zl3 = b2f(zlu.w);
    float4 a4 = *(const float4*)(att + lane * 4);
    size_t idx = (size_t)n * DHID + lane * 4;
    float4 rres = *(const float4*)(hn + idx);

    float m = -3.0e38f, denom = 0.f;
    float ax = 0.f, ay = 0.f, az = 0.f, aw = 0.f;

    const uint2* zrp = (const uint2*)(zb + 256);  // row n: zrp[n*128 + lane]
    uint2 c0 = make_uint2(0, 0), c1 = make_uint2(0, 0);
    if (start < end) {
        int i0 = ssrc[start];
        int i1 = ssrc[(start + 1 < end) ? start + 1 : start];
        c0 = zrp[(size_t)i0 * 128 + lane];
        c1 = zrp[(size_t)i1 * 128 + lane];
    }
    for (int p = start; p < end; p += 2) {
        uint2 u0 = c0, u1 = c1;
        bool val1 = (p + 1 < end);
        if (p + 2 < end) {
            int j0 = ssrc[p + 2];
            int j1 = ssrc[(p + 3 < end) ? p + 3 : p + 2];
            c0 = zrp[(size_t)j0 * 128 + lane];
            c1 = zrp[(size_t)j1 * 128 + lane];
        }
        float z00, z01, z02, z03, z10, z11, z12, z13;
        b2f2(u0.x, z00, z01); b2f2(u0.y, z02, z03);
        b2f2(u1.x, z10, z11); b2f2(u1.y, z12, z13);

        float v0 = zl0 + z00, v1 = zl1 + z01, v2 = zl2 + z02, v3 = zl3 + z03;
        float t0 = zl0 + z10, t1 = zl1 + z11, t2 = zl2 + z12, t3 = zl3 + z13;
        v0 = (v0 > 0.f) ? v0 : 0.2f * v0;
        v1 = (v1 > 0.f) ? v1 : 0.2f * v1;
        v2 = (v2 > 0.f) ? v2 : 0.2f * v2;
        v3 = (v3 > 0.f) ? v3 : 0.2f * v3;
        t0 = (t0 > 0.f) ? t0 : 0.2f * t0;
        t1 = (t1 > 0.f) ? t1 : 0.2f * t1;
        t2 = (t2 > 0.f) ? t2 : 0.2f * t2;
        t3 = (t3 > 0.f) ? t3 : 0.2f * t3;
        float part0 = a4.x * v0 + a4.y * v1 + a4.z * v2 + a4.w * v3;
        float part1 = a4.x * t0 + a4.y * t1 + a4.z * t2 + a4.w * t3;
        float sp0 = quad16_sum(part0);      // per-head (quad) score
        float sp1 = quad16_sum(part1);
        if (!val1) sp1 = -3.0e38f;          // sentinel: weight underflows to 0
        float newm = fmaxf(m, fmaxf(sp0, sp1));
        float corr = __expf(m - newm);      // 0 on first pair
        float w0 = __expf(sp0 - newm);
        float w1 = __expf(sp1 - newm);
        denom = denom * corr + w0 + w1;
        ax = ax * corr + w0 * z00 + w1 * z10;
        ay = ay * corr + w0 * z01 + w1 * z11;
        az = az * corr + w0 * z02 + w1 * z12;
        aw = aw * corr + w0 * z03 + w1 * z13;
        m = newm;
    }
    float inv = 1.0f / (denom + 1e-9f);
    float4 o;
    o.x = ax * inv + rres.x;
    o.y = ay * inv + rres.y;
    o.z = az * inv + rres.z;
    o.w = aw * inv + rres.w;
    float sum = wave_sum(o.x + o.y + o.z + o.w);
    float sq  = wave_sum(o.x * o.x + o.y * o.y + o.z * o.z + o.w * o.w);
    float mean = sum * (1.0f / DHID);
    float var  = sq * (1.0f / DHID) - mean * mean;
    float rr = rsqrtf(fmaxf(var, 0.0f) + 1e-3f);
    float4 gv = *(const float4*)(g + lane * 4);
    float4 bv = *(const float4*)(b + lane * 4);
    float4 y;
    y.x = (o.x - mean) * rr * gv.x + bv.x;
    y.y = (o.y - mean) * rr * gv.y + bv.y;
    y.z = (o.z - mean) * rr * gv.z + bv.z;
    y.w = (o.w - mean) * rr * gv.w + bv.w;
    *(float4*)(xr + idx) = y;
    ushort4 ob;
    ob.x = f2b(y.x); ob.y = f2b(y.y); ob.z = f2b(y.z); ob.w = f2b(y.w);
    *(ushort4*)(xrb + idx) = ob;
}

// ---------------------------------------------------------------- host

extern "C" void kernel_launch(void* const* d_in, const int* in_sizes, int n_in,
                              void* d_out, int out_size, void* d_ws, size_t ws_size,
                              hipStream_t stream) {
    const float* x       = (const float*)d_in[0];
    const float* head_W  = (const float*)d_in[1];
    const float* head_b  = (const float*)d_in[2];
    const float* ng_g    = (const float*)d_in[3];
    const float* ng_b    = (const float*)d_in[4];
    const float* Wl      = (const float*)d_in[5];
    const float* Wr      = (const float*)d_in[6];
    const float* att     = (const float*)d_in[7];
    const float* nd_g    = (const float*)d_in[8];
    const float* nd_b    = (const float*)d_in[9];
    const float* dense_W = (const float*)d_in[10];
    const float* dense_b = (const float*)d_in[11];
    const float* tail_W  = (const float*)d_in[12];
    const float* tail_b  = (const float*)d_in[13];
    const int*   edges   = (const int*)d_in[14];
    float* out = (float*)d_out;

    const size_t NH = (size_t)NN * DHID;  // 5,120,000
    // ---- workspace layout (liveness-checked; zb/d union is deliberate) ----
    float* xr = (float*)d_ws;                           // NH f32  (head-out, then agg out)
    float* hn = xr + NH;                                // NH f32  (LN out, GAT residual)
    unsigned short* hnb = (unsigned short*)(hn + NH);   // NH bf16 (x-bf16 / LN-out bf16 / final hb)
    unsigned short* xrb = hnb + NH;                     // NH bf16
    unsigned short* U   = xrb + NH;                     // union region, 4*NH shorts (40.96 MB)
    unsigned short* zb  = U;                            //   N x 512 bf16   (dies at gat_fused)
    unsigned short* d_buf = U;                          //   N x 1024 bf16  (written after gat_fused, dies at ln_dense)
    unsigned short* headT  = U + 4 * NH;
    unsigned short* WzT    = headT + 65536;             // 4 x (512 x 256)
    unsigned short* denseT = WzT + 524288;              // 4 x (1024 x 256)
    unsigned short* tailT  = denseT + 1048576;          // 64 x 256
    int* counts = (int*)(tailT + 16384);
    int* bsums  = counts + NN;
    int* excl   = bsums + 32;
    int* indptr = excl + NN;
    int* cursor = indptr + NN + 1;
    int* ssrc   = cursor + NN;

    // CSR build
    hipMemsetAsync(counts, 0, NN * sizeof(int), stream);
    hist_kernel<<<(EE + 255) / 256, 256, 0, stream>>>(edges, counts, EE);
    scan_block<<<(NN + 1023) / 1024, 1024, 0, stream>>>(counts, excl, bsums, NN);
    scan_tops<<<1, 64, 0, stream>>>(bsums, (NN + 1023) / 1024);
    scan_fix<<<(NN + 255) / 256, 256, 0, stream>>>(excl, bsums, indptr, cursor, NN);
    scatter_kernel<<<(EE + 255) / 256, 256, 0, stream>>>(edges, cursor, ssrc, EE);

    // weight prep
    transpose_bf16<<<dim3(8, 8, 1), 256, 0, stream>>>(head_W, headT, 256, 256, 0, 0);
    transpose_bf16<<<dim3(8, 8, 4), 256, 0, stream>>>(Wl, WzT, 256, 256, 65536, 131072);
    transpose_bf16<<<dim3(8, 8, 4), 256, 0, stream>>>(Wr, WzT + 65536, 256, 256, 65536, 131072);
    transpose_bf16<<<dim3(32, 8, 4), 256, 0, stream>>>(dense_W, denseT, 256, 1024, 262144, 262144);
    transpose_bf16<<<dim3(2, 8, 1), 256, 0, stream>>>(tail_W, tailT, 256, 64, 0, 0);
    // bf16(x) -> hnb (dead region at this point)
    convert_bf16<<<(int)(NH / 4 + 255) / 256, 256, 0, stream>>>(x, hnb, (int)(NH / 4));

    const int GXP = 160;  // padded to multiple of 8 -> XCD = bx & 7 for every by
    // head: xr = x @ head_W + head_b (fp32)
    gemm128<0><<<dim3(GXP, 2), 256, 0, stream>>>(hnb, headT, head_b, xr, NN, 256);

    for (int l = 0; l < 4; ++l) {
        if (l == 0)
            ln_kernel<<<NN / 4, 256, 0, stream>>>(xr, ng_g, ng_b, hn, hnb, NN);
        else
            ln_dense<<<NN / 4, 256, 0, stream>>>(d_buf, xr, ng_g + l * 256, ng_b + l * 256, hn, hnb, NN);
        // [zl|zr] = hn @ [Wl|Wr]
        gemm128<1><<<dim3(GXP, 4), 256, 0, stream>>>(hnb, WzT + (size_t)l * 131072, nullptr, zb, NN, 512);
        // fused scores + online-softmax agg + residual + LayerNorm
        gat_fused<<<(NN + 3) / 4, 256, 0, stream>>>(zb, att + l * 256, ssrc, indptr, hn,
                                                    nd_g + l * 256, nd_b + l * 256, xr, xrb, NN);
        // d = gelu(xr @ dense_W + dense_b)  (partial chunks, bf16) — clobbers zb (dead)
        gemm128<2><<<dim3(GXP, 8), 256, 0, stream>>>(xrb, denseT + (size_t)l * 262144,
                                                     dense_b + l * 1024, d_buf, NN, 1024);
    }
    // hb = bf16(sum_c d + xr) -> hnb (dead); out = hb @ tail_W + tail_b
    combine_final<<<NN / 4, 256, 0, stream>>>(d_buf, xr, hnb, NN);
    gemm128<0><<<dim3(GXP, 1), 256, 0, stream>>>(hnb, tailT, tail_b, out, NN, 64);
}